// Round 11
// baseline (373.532 us; speedup 1.0000x reference)
//
#include <hip/hip_runtime.h>

// Problem constants (match reference setup_inputs)
#define BB   512
#define NN   512
#define NNZ  8192
#define EMB  64
#define HID  100
#define DUMPC 512            // dump column for merged-away duplicates (in pad, never read)
#define ASTR 528             // A_d row stride in u16 — measured low-conflict (r6: 314K)
#define SROWS 32             // stripe rows: 33.8KB LDS -> 4 blocks/CU (16 waves/CU)

// ---------------------------------------------------------------------------
// ws layout (bytes):
//   [0)          csr_rc  int  [B*NNZ]  (row<<16|col)   16,777,216
//   [16777216)   csr_v   bf16 [B*NNZ]                   8,388,608
//   [25165824)   row_st  int  [B*513]                   1,050,624
//   [26216448)   supT    bf16 [B][112][512]            58,720,256
//   [84936704)   w1t     bf16 [112][64]                    14,336
//   [84951040)   w2t     bf16 [112][128]                   28,672
// h1 (bf16 [B][512][112]) lives in d_out; overwritten by final fp32 output.
// ---------------------------------------------------------------------------
#define OFF_CSR_RC  0
#define OFF_CSR_V   16777216
#define OFF_ROWST   25165824
#define OFF_SUPT    26216448
#define OFF_W1T     84936704
#define OFF_W2T     84951040

typedef __attribute__((ext_vector_type(8))) short short8;
typedef __attribute__((ext_vector_type(4))) float floatx4;

__device__ __forceinline__ unsigned short f2bf(float f) {
    unsigned u = __float_as_uint(f);
    unsigned r = (u + 0x7fffu + ((u >> 16) & 1u)) >> 16;
    return (unsigned short)r;
}

__device__ __forceinline__ short8 pack8(float4 a, float4 b) {
    short8 s;
    s[0] = (short)f2bf(a.x); s[1] = (short)f2bf(a.y);
    s[2] = (short)f2bf(a.z); s[3] = (short)f2bf(a.w);
    s[4] = (short)f2bf(b.x); s[5] = (short)f2bf(b.y);
    s[6] = (short)f2bf(b.z); s[7] = (short)f2bf(b.w);
    return s;
}

// ---------------------------------------------------------------------------
// Prep: transposed bf16 weight panels (zero-padded).
// ---------------------------------------------------------------------------
__global__ __launch_bounds__(256) void k_prep(
    const float* __restrict__ W1, const float* __restrict__ W2,
    unsigned short* __restrict__ w1t, unsigned short* __restrict__ w2t)
{
    int id = blockIdx.x * 256 + threadIdx.x;
    if (id < 112 * 64) {
        int h = id >> 6, k = id & 63;
        float f = (h < 100) ? W1[k * 100 + h] : 0.f;
        w1t[id] = f2bf(f);
    }
    if (id < 112 * 128) {
        int h = id >> 7, k = id & 127;
        float f = (h < 100 && k < 100) ? W2[k * 100 + h] : 0.f;
        w2t[id] = f2bf(f);
    }
}

// ---------------------------------------------------------------------------
// CSR build, all-LDS (verified rounds 5-10); csr_v stored bf16.
// ---------------------------------------------------------------------------
__global__ __launch_bounds__(512) void k_csr_build(
    const int* __restrict__ rows, const int* __restrict__ cols,
    const float* __restrict__ vals, int* __restrict__ row_start,
    int* __restrict__ csr_rc, unsigned short* __restrict__ csr_v)
{
    __shared__ int   rl[NNZ];
    __shared__ float vl[NNZ];
    __shared__ int   cnt[NN];
    __shared__ int   sc[NN];

    const int b   = blockIdx.x;
    const int tid = threadIdx.x;       // 0..511 == NN

    const int*   rb = rows + (size_t)b * NNZ;
    const int*   cb = cols + (size_t)b * NNZ;
    const float* vb = vals + (size_t)b * NNZ;

    cnt[tid] = 0;
    __syncthreads();

    #pragma unroll
    for (int i = 0; i < NNZ / 512; ++i)
        atomicAdd(&cnt[rb[tid + i * 512]], 1);
    __syncthreads();

    const int own = cnt[tid];
    sc[tid] = own;
    __syncthreads();
    #pragma unroll
    for (int off = 1; off < NN; off <<= 1) {
        int v = (tid >= off) ? sc[tid - off] : 0;
        __syncthreads();
        sc[tid] += v;
        __syncthreads();
    }
    row_start[b * 513 + tid + 1] = sc[tid];
    if (tid == 0) row_start[b * 513] = 0;
    cnt[tid] = sc[tid] - own;
    __syncthreads();

    #pragma unroll
    for (int i = 0; i < NNZ / 512; ++i) {
        int idx = tid + i * 512;
        int   r = rb[idx];
        int   c = cb[idx];
        float v = vb[idx];
        int pos = atomicAdd(&cnt[r], 1);
        rl[pos] = (r << 16) | c;
        vl[pos] = v;
    }
    __syncthreads();

    // per-row duplicate merge (duplicates redirected to DUMPC)
    {
        const int s = sc[tid] - own;
        const int e = sc[tid];
        for (int j = s; j < e - 1; ++j) {
            int pj = rl[j];
            if ((pj & 0xffff) == DUMPC) continue;
            float add = 0.f;
            bool mod = false;
            for (int j2 = j + 1; j2 < e; ++j2) {
                if (rl[j2] == pj) {
                    add += vl[j2];
                    rl[j2] = (pj & 0xffff0000) | DUMPC;
                    mod = true;
                }
            }
            if (mod) vl[j] += add;
        }
    }
    __syncthreads();

    #pragma unroll
    for (int i = 0; i < NNZ / 512; ++i) {
        int idx = tid + i * 512;
        csr_rc[(size_t)b * NNZ + idx] = rl[idx];
        csr_v [(size_t)b * NNZ + idx] = f2bf(vl[idx]);
    }
}

// ---------------------------------------------------------------------------
// GEMM1 (MFMA): supT[b][col][row] = bf16( emb[hyper] @ W1 ).  (verified r6-r10)
// ---------------------------------------------------------------------------
__global__ __launch_bounds__(256) void k_gemm1_mfma(
    const int* __restrict__ hyper, const float* __restrict__ emb,
    const unsigned short* __restrict__ w1t, unsigned short* __restrict__ supT)
{
    const int lane = threadIdx.x & 63, wave = threadIdx.x >> 6;
    const int l15 = lane & 15, g4 = lane >> 4;

    short8 bq[7][2];
    #pragma unroll
    for (int ct = 0; ct < 7; ++ct)
        #pragma unroll
        for (int kt = 0; kt < 2; ++kt)
            bq[ct][kt] = *(const short8*)(w1t + (ct * 16 + l15) * 64 + kt * 32 + g4 * 8);

    const int wsid = blockIdx.x * 4 + wave;
    #pragma unroll 2
    for (int i = 0; i < 4; ++i) {
        const int  rb   = wsid * 4 + i;
        const long base = (long)rb * 16;
        const int  rid  = hyper[base + l15];
        const float* ep = emb + (long)rid * EMB + g4 * 8;
        float4 f0 = *(const float4*)(ep);
        float4 f1 = *(const float4*)(ep + 4);
        float4 f2 = *(const float4*)(ep + 32);
        float4 f3 = *(const float4*)(ep + 36);
        short8 a0 = pack8(f0, f1);
        short8 a1 = pack8(f2, f3);

        floatx4 acc[7];
        #pragma unroll
        for (int ct = 0; ct < 7; ++ct) acc[ct] = (floatx4)0.f;
        #pragma unroll
        for (int ct = 0; ct < 7; ++ct) {
            acc[ct] = __builtin_amdgcn_mfma_f32_16x16x32_bf16(a0, bq[ct][0], acc[ct], 0, 0, 0);
            acc[ct] = __builtin_amdgcn_mfma_f32_16x16x32_bf16(a1, bq[ct][1], acc[ct], 0, 0, 0);
        }

        const int batch = rb >> 5;
        const int inrow = (rb & 31) * 16 + g4 * 4;
        unsigned short* sp = supT + (size_t)batch * 57344 + inrow;
        #pragma unroll
        for (int ct = 0; ct < 7; ++ct) {
            int col = ct * 16 + l15;
            uint2 w;
            w.x = (unsigned)f2bf(acc[ct][0]) | ((unsigned)f2bf(acc[ct][1]) << 16);
            w.y = (unsigned)f2bf(acc[ct][2]) | ((unsigned)f2bf(acc[ct][3]) << 16);
            *(uint2*)(sp + (size_t)col * 512) = w;
        }
    }
}

// ---------------------------------------------------------------------------
// GEMM2 (MFMA): supT[b][col][row] = bf16( h1 @ W2 ), h1 bf16 [512][112] in
// d_out. k>=112 fragments predicated to zero (replay-safe).  (verified r7-r10)
// ---------------------------------------------------------------------------
__global__ __launch_bounds__(256) void k_gemm2_mfma(
    const unsigned short* __restrict__ h1, const unsigned short* __restrict__ w2t,
    unsigned short* __restrict__ supT)
{
    const int lane = threadIdx.x & 63, wave = threadIdx.x >> 6;
    const int l15 = lane & 15, g4 = lane >> 4;
    const int ct0 = (wave & 1) ? 4 : 0;

    short8 bq[4][4];
    #pragma unroll
    for (int ctl = 0; ctl < 4; ++ctl) {
        int ct = ct0 + ctl;
        if (ct < 7)
            #pragma unroll
            for (int kt = 0; kt < 4; ++kt)
                bq[ctl][kt] = *(const short8*)(w2t + (ct * 16 + l15) * 128 + kt * 32 + g4 * 8);
    }

    const int wp = blockIdx.x * 2 + (wave >> 1);
    #pragma unroll 2
    for (int i = 0; i < 8; ++i) {
        const int  rb   = wp * 8 + i;
        const long base = (long)rb * 16;
        const unsigned short* rp = h1 + (size_t)(base + l15) * 112;

        short8 a[4];
        #pragma unroll
        for (int kt = 0; kt < 4; ++kt) {
            int k0 = kt * 32 + g4 * 8;
            short8 av = (short8)(short)0;
            if (k0 < 112) av = *(const short8*)(rp + k0);
            a[kt] = av;
        }

        floatx4 acc[4];
        #pragma unroll
        for (int ctl = 0; ctl < 4; ++ctl) acc[ctl] = (floatx4)0.f;
        #pragma unroll
        for (int ctl = 0; ctl < 4; ++ctl) {
            if (ct0 + ctl < 7) {
                #pragma unroll
                for (int kt = 0; kt < 4; ++kt)
                    acc[ctl] = __builtin_amdgcn_mfma_f32_16x16x32_bf16(a[kt], bq[ctl][kt], acc[ctl], 0, 0, 0);
            }
        }

        const int batch = rb >> 5;
        const int inrow = (rb & 31) * 16 + g4 * 4;
        unsigned short* sp = supT + (size_t)batch * 57344 + inrow;
        #pragma unroll
        for (int ctl = 0; ctl < 4; ++ctl) {
            if (ct0 + ctl < 7) {
                int col = (ct0 + ctl) * 16 + l15;
                uint2 w;
                w.x = (unsigned)f2bf(acc[ctl][0]) | ((unsigned)f2bf(acc[ctl][1]) << 16);
                w.y = (unsigned)f2bf(acc[ctl][2]) | ((unsigned)f2bf(acc[ctl][3]) << 16);
                *(uint2*)(sp + (size_t)col * 512) = w;
            }
        }
    }
}

// ---------------------------------------------------------------------------
// SpMM + bias via dense-A MFMA. 32-ROW stripes: A_d[32][528] = 33.8 KB ->
// 4 blocks/CU = 16 waves/CU (4 MFMA-issuing waves/SIMD, 2x r10 — the kernel
// is MFMA-issue-concurrency bound: 34k cy of MFMA per SIMD per dispatch).
// 8192 x 256-thr blocks; wave owns n-tiles {2w,2w+1} x 2 m-tiles x 16 kt.
// Inner loop = r8/r10's exact load-in-loop shape (no manual chaining — r9
// lesson). Direct C writes (r6: 314K conflicts w/ ASTR 528). XCD swizzle:
// 16 consecutive blocks per batch per XCD (panel L2-resident, FETCH 41MB
// proven r8). Early-scatter regs (T14) kept.
// ---------------------------------------------------------------------------
template<bool FINAL>
__global__ __launch_bounds__(256) void k_spmm_mfma(
    const int* __restrict__ row_st, const int* __restrict__ rc,
    const unsigned short* __restrict__ vv, const unsigned short* __restrict__ supT,
    const float* __restrict__ bias, unsigned short* __restrict__ h1,
    float* __restrict__ out)
{
    __shared__ unsigned short Ad[SROWS * ASTR];  // 33,792 B -> 4 blocks/CU

    const int tid    = threadIdx.x;
    // XCD-locality swizzle (8 XCDs, round-robin blockIdx%8 -> XCD)
    const int xcd    = blockIdx.x & 7;
    const int local  = blockIdx.x >> 3;          // 0..1023
    const int batch  = xcd * 64 + (local >> 4);
    const int stripe = local & 15;
    const int r0     = stripe * SROWS;

    // P0: issue CSR loads EARLY (use-late after the zero phase)
    const int s0 = row_st[batch * 513 + r0];
    const int e0 = row_st[batch * 513 + r0 + SROWS];
    const int*            rcb = rc + (size_t)batch * NNZ;
    const unsigned short* vvb = vv + (size_t)batch * NNZ;
    int            pc[3];
    unsigned short pv[3];
    #pragma unroll
    for (int i = 0; i < 3; ++i) {
        int idx = s0 + tid + i * 256;
        bool ok = idx < e0;
        pc[i] = ok ? rcb[idx] : 0;
        pv[i] = ok ? vvb[idx] : 0;
    }

    // P1: zero A_d (32*528/8 = 2112 uint4)
    {
        uint4* z = (uint4*)Ad;
        #pragma unroll
        for (int i = 0; i < 9; ++i) {
            int idx = tid + i * 256;
            if (idx < SROWS * ASTR / 8) z[idx] = make_uint4(0u, 0u, 0u, 0u);
        }
    }
    __syncthreads();

    // P2: scatter from regs (dup-free; DUMPC lands in pad)
    #pragma unroll
    for (int i = 0; i < 3; ++i) {
        int idx = s0 + tid + i * 256;
        if (idx < e0)
            Ad[((pc[i] >> 16) - r0) * ASTR + (pc[i] & 0xffff)] = pv[i];
    }
    // overflow fallback (cnt > 768: ~never at Poisson(512), correctness only)
    for (int idx = s0 + 768 + tid; idx < e0; idx += 256) {
        int p = rcb[idx];
        Ad[((p >> 16) - r0) * ASTR + (p & 0xffff)] = vvb[idx];
    }
    __syncthreads();

    // P3: MFMA — C[32 x 112]; wave owns n-tiles {2w, 2w+1}, both m-tiles
    const int lane = tid & 63, wave = tid >> 6;
    const int l15 = lane & 15, g4 = lane >> 4;
    const int nt0 = wave * 2;
    const bool two = (nt0 + 1) < 7;              // wave3 owns only n-tile 6

    const unsigned short* b0p = supT + (size_t)batch * 57344 + (nt0 * 16 + l15) * 512 + g4 * 8;
    const unsigned short* b1p = b0p + 16 * 512;
    const unsigned short* ap  = Ad + l15 * ASTR + g4 * 8;

    floatx4 acc[2][2];                           // [n][m]
    #pragma unroll
    for (int n = 0; n < 2; ++n)
        #pragma unroll
        for (int m = 0; m < 2; ++m) acc[n][m] = (floatx4)0.f;

    #pragma unroll 4
    for (int kt = 0; kt < 16; ++kt) {
        short8 b0 = *(const short8*)(b0p + kt * 32);
        short8 b1 = (short8)(short)0;
        if (two) b1 = *(const short8*)(b1p + kt * 32);
        #pragma unroll
        for (int m = 0; m < 2; ++m) {
            short8 a = *(const short8*)(ap + m * 16 * ASTR + kt * 32);
            acc[0][m] = __builtin_amdgcn_mfma_f32_16x16x32_bf16(a, b0, acc[0][m], 0, 0, 0);
            if (two)
                acc[1][m] = __builtin_amdgcn_mfma_f32_16x16x32_bf16(a, b1, acc[1][m], 0, 0, 0);
        }
    }

    // P4: C write + bias (direct; r6-measured conflict-clean with ASTR 528)
    #pragma unroll
    for (int nn = 0; nn < 2; ++nn) {
        int nt = nt0 + nn;
        if (nt >= 7) break;
        int col = nt * 16 + l15;
        if (FINAL) {
            if (col < HID) {
                float bi = bias[col];
                #pragma unroll
                for (int m = 0; m < 2; ++m) {
                    int row = r0 + m * 16 + g4 * 4;
                    float* op = out + ((size_t)batch * NN + row) * HID + col;
                    #pragma unroll
                    for (int q = 0; q < 4; ++q)
                        op[(size_t)q * HID] = acc[nn][m][q] + bi;
                }
            }
        } else {
            float bi = (col < HID) ? bias[col] : 0.f;  // pad cols: acc==0 -> 0
            #pragma unroll
            for (int m = 0; m < 2; ++m) {
                int row = r0 + m * 16 + g4 * 4;
                unsigned short* hp = h1 + ((size_t)batch * NN + row) * 112 + col;
                #pragma unroll
                for (int q = 0; q < 4; ++q)
                    hp[(size_t)q * 112] = f2bf(acc[nn][m][q] + bi);
            }
        }
    }
}

// ---------------------------------------------------------------------------
extern "C" void kernel_launch(void* const* d_in, const int* in_sizes, int n_in,
                              void* d_out, int out_size, void* d_ws, size_t ws_size,
                              hipStream_t stream)
{
    const int*   hyper = (const int*)  d_in[0];
    const int*   arows = (const int*)  d_in[1];
    const int*   acols = (const int*)  d_in[2];
    const float* avals = (const float*)d_in[3];
    const float* emb   = (const float*)d_in[4];
    const float* W1    = (const float*)d_in[5];
    const float* b1    = (const float*)d_in[6];
    const float* W2    = (const float*)d_in[7];
    const float* b2    = (const float*)d_in[8];

    float*          out = (float*)d_out;
    unsigned short* h1  = (unsigned short*)d_out;   // bf16 [B][512][112] view
    char*           ws  = (char*)d_ws;

    int*            csr_rc = (int*)           (ws + OFF_CSR_RC);
    unsigned short* csr_v  = (unsigned short*)(ws + OFF_CSR_V);
    int*            row_st = (int*)           (ws + OFF_ROWST);
    unsigned short* supT   = (unsigned short*)(ws + OFF_SUPT);
    unsigned short* w1t    = (unsigned short*)(ws + OFF_W1T);
    unsigned short* w2t    = (unsigned short*)(ws + OFF_W2T);

    // prep transposed bf16 weights
    k_prep<<<56, 256, 0, stream>>>(W1, W2, w1t, w2t);

    // CSR build (all-LDS; A shared by both layers)
    k_csr_build<<<BB, 512, 0, stream>>>(arows, acols, avals, row_st, csr_rc, csr_v);

    // 1) supT = bf16(emb[hyper] @ W1)^T (per batch)
    k_gemm1_mfma<<<1024, 256, 0, stream>>>(hyper, emb, w1t, supT);
    // 2) h1 = bf16(A @ sup1 + b1) -> d_out (bf16 [512][112])
    k_spmm_mfma<false><<<BB * 16, 256, 0, stream>>>(row_st, csr_rc, csr_v, supT, b1, h1, out);
    // 3) supT = bf16(h1 @ W2)^T (per batch)
    k_gemm2_mfma<<<1024, 256, 0, stream>>>(h1, w2t, supT);
    // 4) out = A @ sup2 + b2 -> d_out (fp32)
    k_spmm_mfma<true><<<BB * 16, 256, 0, stream>>>(row_st, csr_rc, csr_v, supT, b2, h1, out);
}

// Round 12
// 280.697 us; speedup vs baseline: 1.3307x; 1.3307x over previous
//
#include <hip/hip_runtime.h>

// Problem constants (match reference setup_inputs)
#define BB   512
#define NN   512
#define NNZ  8192
#define EMB  64
#define HID  100
#define DUMPC 512            // dump "column" for merged-away duplicates -> LDS tail

// ---------------------------------------------------------------------------
// ws layout (bytes):
//   [0)          csr_rc  int  [B*NNZ]  (row<<16|col)   16,777,216
//   [16777216)   csr_v   bf16 [B*NNZ]                   8,388,608
//   [25165824)   row_st  int  [B*513]                   1,050,624
//   [26216448)   supT    bf16 [B][16kt][112col][32k]   58,720,256   (k-tiled!)
//   [84936704)   w1t     bf16 [112][64]                    14,336
//   [84951040)   w2t     bf16 [112][128]                   28,672
// h1 (bf16 [B][512][112]) lives in d_out; overwritten by final fp32 output.
// ---------------------------------------------------------------------------
#define OFF_CSR_RC  0
#define OFF_CSR_V   16777216
#define OFF_ROWST   25165824
#define OFF_SUPT    26216448
#define OFF_W1T     84936704
#define OFF_W2T     84951040

typedef __attribute__((ext_vector_type(8))) short short8;
typedef __attribute__((ext_vector_type(4))) float floatx4;

__device__ __forceinline__ unsigned short f2bf(float f) {
    unsigned u = __float_as_uint(f);
    unsigned r = (u + 0x7fffu + ((u >> 16) & 1u)) >> 16;
    return (unsigned short)r;
}

__device__ __forceinline__ short8 pack8(float4 a, float4 b) {
    short8 s;
    s[0] = (short)f2bf(a.x); s[1] = (short)f2bf(a.y);
    s[2] = (short)f2bf(a.z); s[3] = (short)f2bf(a.w);
    s[4] = (short)f2bf(b.x); s[5] = (short)f2bf(b.y);
    s[6] = (short)f2bf(b.z); s[7] = (short)f2bf(b.w);
    return s;
}

// supT k-tiled addressing: elem(b, col, k) = b*57344 + (k>>5)*3584 + col*32 + (k&31)
__device__ __forceinline__ size_t supt_addr(int batch, int col, int k) {
    return (size_t)batch * 57344 + (size_t)(k >> 5) * 3584 + (size_t)col * 32 + (k & 31);
}

// ---------------------------------------------------------------------------
// Prep: transposed bf16 weight panels (zero-padded).
// ---------------------------------------------------------------------------
__global__ __launch_bounds__(256) void k_prep(
    const float* __restrict__ W1, const float* __restrict__ W2,
    unsigned short* __restrict__ w1t, unsigned short* __restrict__ w2t)
{
    int id = blockIdx.x * 256 + threadIdx.x;
    if (id < 112 * 64) {
        int h = id >> 6, k = id & 63;
        float f = (h < 100) ? W1[k * 100 + h] : 0.f;
        w1t[id] = f2bf(f);
    }
    if (id < 112 * 128) {
        int h = id >> 7, k = id & 127;
        float f = (h < 100 && k < 100) ? W2[k * 100 + h] : 0.f;
        w2t[id] = f2bf(f);
    }
}

// ---------------------------------------------------------------------------
// CSR build, all-LDS (verified rounds 5-11); csr_v stored bf16.
// ---------------------------------------------------------------------------
__global__ __launch_bounds__(512) void k_csr_build(
    const int* __restrict__ rows, const int* __restrict__ cols,
    const float* __restrict__ vals, int* __restrict__ row_start,
    int* __restrict__ csr_rc, unsigned short* __restrict__ csr_v)
{
    __shared__ int   rl[NNZ];
    __shared__ float vl[NNZ];
    __shared__ int   cnt[NN];
    __shared__ int   sc[NN];

    const int b   = blockIdx.x;
    const int tid = threadIdx.x;       // 0..511 == NN

    const int*   rb = rows + (size_t)b * NNZ;
    const int*   cb = cols + (size_t)b * NNZ;
    const float* vb = vals + (size_t)b * NNZ;

    cnt[tid] = 0;
    __syncthreads();

    #pragma unroll
    for (int i = 0; i < NNZ / 512; ++i)
        atomicAdd(&cnt[rb[tid + i * 512]], 1);
    __syncthreads();

    const int own = cnt[tid];
    sc[tid] = own;
    __syncthreads();
    #pragma unroll
    for (int off = 1; off < NN; off <<= 1) {
        int v = (tid >= off) ? sc[tid - off] : 0;
        __syncthreads();
        sc[tid] += v;
        __syncthreads();
    }
    row_start[b * 513 + tid + 1] = sc[tid];
    if (tid == 0) row_start[b * 513] = 0;
    cnt[tid] = sc[tid] - own;
    __syncthreads();

    #pragma unroll
    for (int i = 0; i < NNZ / 512; ++i) {
        int idx = tid + i * 512;
        int   r = rb[idx];
        int   c = cb[idx];
        float v = vb[idx];
        int pos = atomicAdd(&cnt[r], 1);
        rl[pos] = (r << 16) | c;
        vl[pos] = v;
    }
    __syncthreads();

    // per-row duplicate merge (duplicates redirected to DUMPC)
    {
        const int s = sc[tid] - own;
        const int e = sc[tid];
        for (int j = s; j < e - 1; ++j) {
            int pj = rl[j];
            if ((pj & 0xffff) == DUMPC) continue;
            float add = 0.f;
            bool mod = false;
            for (int j2 = j + 1; j2 < e; ++j2) {
                if (rl[j2] == pj) {
                    add += vl[j2];
                    rl[j2] = (pj & 0xffff0000) | DUMPC;
                    mod = true;
                }
            }
            if (mod) vl[j] += add;
        }
    }
    __syncthreads();

    #pragma unroll
    for (int i = 0; i < NNZ / 512; ++i) {
        int idx = tid + i * 512;
        csr_rc[(size_t)b * NNZ + idx] = rl[idx];
        csr_v [(size_t)b * NNZ + idx] = f2bf(vl[idx]);
    }
}

// ---------------------------------------------------------------------------
// GEMM1 (MFMA): supT(k-tiled) = bf16( emb[hyper] @ W1 )^T per batch.
// Only the store addressing differs from the r6-r11 verified kernel.
// ---------------------------------------------------------------------------
__global__ __launch_bounds__(256) void k_gemm1_mfma(
    const int* __restrict__ hyper, const float* __restrict__ emb,
    const unsigned short* __restrict__ w1t, unsigned short* __restrict__ supT)
{
    const int lane = threadIdx.x & 63, wave = threadIdx.x >> 6;
    const int l15 = lane & 15, g4 = lane >> 4;

    short8 bq[7][2];
    #pragma unroll
    for (int ct = 0; ct < 7; ++ct)
        #pragma unroll
        for (int kt = 0; kt < 2; ++kt)
            bq[ct][kt] = *(const short8*)(w1t + (ct * 16 + l15) * 64 + kt * 32 + g4 * 8);

    const int wsid = blockIdx.x * 4 + wave;
    #pragma unroll 2
    for (int i = 0; i < 4; ++i) {
        const int  rb   = wsid * 4 + i;
        const long base = (long)rb * 16;
        const int  rid  = hyper[base + l15];
        const float* ep = emb + (long)rid * EMB + g4 * 8;
        float4 f0 = *(const float4*)(ep);
        float4 f1 = *(const float4*)(ep + 4);
        float4 f2 = *(const float4*)(ep + 32);
        float4 f3 = *(const float4*)(ep + 36);
        short8 a0 = pack8(f0, f1);
        short8 a1 = pack8(f2, f3);

        floatx4 acc[7];
        #pragma unroll
        for (int ct = 0; ct < 7; ++ct) acc[ct] = (floatx4)0.f;
        #pragma unroll
        for (int ct = 0; ct < 7; ++ct) {
            acc[ct] = __builtin_amdgcn_mfma_f32_16x16x32_bf16(a0, bq[ct][0], acc[ct], 0, 0, 0);
            acc[ct] = __builtin_amdgcn_mfma_f32_16x16x32_bf16(a1, bq[ct][1], acc[ct], 0, 0, 0);
        }

        const int batch = rb >> 5;                   // 32 rowblocks per batch
        const int inrow = (rb & 31) * 16 + g4 * 4;   // k index within batch
        #pragma unroll
        for (int ct = 0; ct < 7; ++ct) {
            int col = ct * 16 + l15;
            uint2 w;
            w.x = (unsigned)f2bf(acc[ct][0]) | ((unsigned)f2bf(acc[ct][1]) << 16);
            w.y = (unsigned)f2bf(acc[ct][2]) | ((unsigned)f2bf(acc[ct][3]) << 16);
            *(uint2*)(supT + supt_addr(batch, col, inrow)) = w;
        }
    }
}

// ---------------------------------------------------------------------------
// GEMM2 (MFMA): supT(k-tiled) = bf16( h1 @ W2 )^T, h1 bf16 [512][112] in
// d_out. k>=112 fragments predicated to zero (replay-safe).
// ---------------------------------------------------------------------------
__global__ __launch_bounds__(256) void k_gemm2_mfma(
    const unsigned short* __restrict__ h1, const unsigned short* __restrict__ w2t,
    unsigned short* __restrict__ supT)
{
    const int lane = threadIdx.x & 63, wave = threadIdx.x >> 6;
    const int l15 = lane & 15, g4 = lane >> 4;
    const int ct0 = (wave & 1) ? 4 : 0;

    short8 bq[4][4];
    #pragma unroll
    for (int ctl = 0; ctl < 4; ++ctl) {
        int ct = ct0 + ctl;
        if (ct < 7)
            #pragma unroll
            for (int kt = 0; kt < 4; ++kt)
                bq[ctl][kt] = *(const short8*)(w2t + (ct * 16 + l15) * 128 + kt * 32 + g4 * 8);
    }

    const int wp = blockIdx.x * 2 + (wave >> 1);
    #pragma unroll 2
    for (int i = 0; i < 8; ++i) {
        const int  rb   = wp * 8 + i;
        const long base = (long)rb * 16;
        const unsigned short* rp = h1 + (size_t)(base + l15) * 112;

        short8 a[4];
        #pragma unroll
        for (int kt = 0; kt < 4; ++kt) {
            int k0 = kt * 32 + g4 * 8;
            short8 av = (short8)(short)0;
            if (k0 < 112) av = *(const short8*)(rp + k0);
            a[kt] = av;
        }

        floatx4 acc[4];
        #pragma unroll
        for (int ctl = 0; ctl < 4; ++ctl) acc[ctl] = (floatx4)0.f;
        #pragma unroll
        for (int ctl = 0; ctl < 4; ++ctl) {
            if (ct0 + ctl < 7) {
                #pragma unroll
                for (int kt = 0; kt < 4; ++kt)
                    acc[ctl] = __builtin_amdgcn_mfma_f32_16x16x32_bf16(a[kt], bq[ctl][kt], acc[ctl], 0, 0, 0);
            }
        }

        const int batch = rb >> 5;
        const int inrow = (rb & 31) * 16 + g4 * 4;
        #pragma unroll
        for (int ctl = 0; ctl < 4; ++ctl) {
            if (ct0 + ctl < 7) {
                int col = (ct0 + ctl) * 16 + l15;
                uint2 w;
                w.x = (unsigned)f2bf(acc[ctl][0]) | ((unsigned)f2bf(acc[ctl][1]) << 16);
                w.y = (unsigned)f2bf(acc[ctl][2]) | ((unsigned)f2bf(acc[ctl][3]) << 16);
                *(uint2*)(supT + supt_addr(batch, col, inrow)) = w;
            }
        }
    }
}

// ---------------------------------------------------------------------------
// SpMM + bias via dense-A MFMA, fragment-contiguous layouts.
// r10 geometry (4096 x 256-thr blocks, 64-row stripes, 2 blocks/CU, XCD
// swizzle, wave = 2 n-tiles x 4 m-tiles — the measured-best MFMA:B-load
// ratio). NEW: supT k-tiled -> each B load = one contiguous 1KB wave chunk;
// A_d LDS tiled [m:4][kt:16][r:16][k:32] (64KB, no pad) -> contiguous
// lane-linear ds_read_b128, conflict-free. Dup entries -> 64-elem LDS tail.
// ---------------------------------------------------------------------------
template<bool FINAL>
__global__ __launch_bounds__(256) void k_spmm_mfma(
    const int* __restrict__ row_st, const int* __restrict__ rc,
    const unsigned short* __restrict__ vv, const unsigned short* __restrict__ supT,
    const float* __restrict__ bias, unsigned short* __restrict__ h1,
    float* __restrict__ out)
{
    __shared__ unsigned short Ad[64 * 512 + 64];  // 65,664 B -> 2 blocks/CU

    const int tid    = threadIdx.x;
    // XCD-locality swizzle (8 XCDs, round-robin blockIdx%8 -> XCD)
    const int xcd    = blockIdx.x & 7;
    const int local  = blockIdx.x >> 3;          // 0..511
    const int batch  = xcd * 64 + (local >> 3);
    const int stripe = local & 7;
    const int r0     = stripe * 64;

    // P0: issue CSR loads EARLY (use-late after the zero phase)
    const int s0 = row_st[batch * 513 + r0];
    const int e0 = row_st[batch * 513 + r0 + 64];
    const int*            rcb = rc + (size_t)batch * NNZ;
    const unsigned short* vvb = vv + (size_t)batch * NNZ;
    int            pc[5];
    unsigned short pv[5];
    #pragma unroll
    for (int i = 0; i < 5; ++i) {
        int idx = s0 + tid + i * 256;
        bool ok = idx < e0;
        pc[i] = ok ? rcb[idx] : 0;
        pv[i] = ok ? vvb[idx] : 0;
    }

    // P1: zero A_d (65,664 B = 4104 uint4)
    {
        uint4* z = (uint4*)Ad;
        #pragma unroll
        for (int i = 0; i < 17; ++i) {
            int idx = tid + i * 256;
            if (idx < 4104) z[idx] = make_uint4(0u, 0u, 0u, 0u);
        }
    }
    __syncthreads();

    // P2: scatter from regs. Tiled addr: [r>>4][c>>5][r&15][c&31].
    //     Dups (c==DUMPC) land in the 64-elem tail (never read).
    #pragma unroll
    for (int i = 0; i < 5; ++i) {
        int idx = s0 + tid + i * 256;
        if (idx < e0) {
            int r = ((pc[i] >> 16) & 0xffff) - r0;
            int c = pc[i] & 0xffff;
            int a = (c < 512) ? ((r >> 4) * 8192 + (c >> 5) * 512 + (r & 15) * 32 + (c & 31))
                              : (64 * 512 + (tid & 63));
            Ad[a] = pv[i];
        }
    }
    // overflow fallback (cnt > 1280: statistically never, correctness only)
    for (int idx = s0 + 1280 + tid; idx < e0; idx += 256) {
        int p = rcb[idx];
        int r = ((p >> 16) & 0xffff) - r0;
        int c = p & 0xffff;
        int a = (c < 512) ? ((r >> 4) * 8192 + (c >> 5) * 512 + (r & 15) * 32 + (c & 31))
                          : (64 * 512 + (tid & 63));
        Ad[a] = vvb[idx];
    }
    __syncthreads();

    // P3: MFMA — C[64 x 112]; wave owns n-tiles {2w, 2w+1}, all 4 m-tiles
    const int lane = tid & 63, wave = tid >> 6;
    const int l15 = lane & 15, g4 = lane >> 4;
    const int nt0 = wave * 2;
    const bool two = (nt0 + 1) < 7;              // wave3 owns only n-tile 6

    // B: contiguous 1KB per (nt,kt): base + kt*3584
    const unsigned short* b0p = supT + (size_t)batch * 57344 + (nt0 * 16 + l15) * 32 + g4 * 8;
    const unsigned short* b1p = b0p + 512;       // next n-tile (+16 cols * 32)
    // A: contiguous 1KB per (m,kt): base + m*8192 + kt*512
    const unsigned short* ap  = Ad + l15 * 32 + g4 * 8;

    floatx4 acc[2][4];
    #pragma unroll
    for (int n = 0; n < 2; ++n)
        #pragma unroll
        for (int m = 0; m < 4; ++m) acc[n][m] = (floatx4)0.f;

    #pragma unroll 4
    for (int kt = 0; kt < 16; ++kt) {
        short8 b0 = *(const short8*)(b0p + (size_t)kt * 3584);
        short8 b1 = (short8)(short)0;
        if (two) b1 = *(const short8*)(b1p + (size_t)kt * 3584);
        #pragma unroll
        for (int m = 0; m < 4; ++m) {
            short8 a = *(const short8*)(ap + m * 8192 + kt * 512);
            acc[0][m] = __builtin_amdgcn_mfma_f32_16x16x32_bf16(a, b0, acc[0][m], 0, 0, 0);
            if (two)
                acc[1][m] = __builtin_amdgcn_mfma_f32_16x16x32_bf16(a, b1, acc[1][m], 0, 0, 0);
        }
    }

    // P4: C write + bias (direct)
    #pragma unroll
    for (int nn = 0; nn < 2; ++nn) {
        int nt = nt0 + nn;
        if (nt >= 7) break;
        int col = nt * 16 + l15;
        if (FINAL) {
            if (col < HID) {
                float bi = bias[col];
                #pragma unroll
                for (int m = 0; m < 4; ++m) {
                    int row = r0 + m * 16 + g4 * 4;
                    float* op = out + ((size_t)batch * NN + row) * HID + col;
                    #pragma unroll
                    for (int q = 0; q < 4; ++q)
                        op[(size_t)q * HID] = acc[nn][m][q] + bi;
                }
            }
        } else {
            float bi = (col < HID) ? bias[col] : 0.f;  // pad cols: acc==0 -> 0
            #pragma unroll
            for (int m = 0; m < 4; ++m) {
                int row = r0 + m * 16 + g4 * 4;
                unsigned short* hp = h1 + ((size_t)batch * NN + row) * 112 + col;
                #pragma unroll
                for (int q = 0; q < 4; ++q)
                    hp[(size_t)q * 112] = f2bf(acc[nn][m][q] + bi);
            }
        }
    }
}

// ---------------------------------------------------------------------------
extern "C" void kernel_launch(void* const* d_in, const int* in_sizes, int n_in,
                              void* d_out, int out_size, void* d_ws, size_t ws_size,
                              hipStream_t stream)
{
    const int*   hyper = (const int*)  d_in[0];
    const int*   arows = (const int*)  d_in[1];
    const int*   acols = (const int*)  d_in[2];
    const float* avals = (const float*)d_in[3];
    const float* emb   = (const float*)d_in[4];
    const float* W1    = (const float*)d_in[5];
    const float* b1    = (const float*)d_in[6];
    const float* W2    = (const float*)d_in[7];
    const float* b2    = (const float*)d_in[8];

    float*          out = (float*)d_out;
    unsigned short* h1  = (unsigned short*)d_out;   // bf16 [B][512][112] view
    char*           ws  = (char*)d_ws;

    int*            csr_rc = (int*)           (ws + OFF_CSR_RC);
    unsigned short* csr_v  = (unsigned short*)(ws + OFF_CSR_V);
    int*            row_st = (int*)           (ws + OFF_ROWST);
    unsigned short* supT   = (unsigned short*)(ws + OFF_SUPT);
    unsigned short* w1t    = (unsigned short*)(ws + OFF_W1T);
    unsigned short* w2t    = (unsigned short*)(ws + OFF_W2T);

    // prep transposed bf16 weights
    k_prep<<<56, 256, 0, stream>>>(W1, W2, w1t, w2t);

    // CSR build (all-LDS; A shared by both layers)
    k_csr_build<<<BB, 512, 0, stream>>>(arows, acols, avals, row_st, csr_rc, csr_v);

    // 1) supT(k-tiled) = bf16(emb[hyper] @ W1)^T (per batch)
    k_gemm1_mfma<<<1024, 256, 0, stream>>>(hyper, emb, w1t, supT);
    // 2) h1 = bf16(A @ sup1 + b1) -> d_out (bf16 [512][112])
    k_spmm_mfma<false><<<BB * 8, 256, 0, stream>>>(row_st, csr_rc, csr_v, supT, b1, h1, out);
    // 3) supT(k-tiled) = bf16(h1 @ W2)^T (per batch)
    k_gemm2_mfma<<<1024, 256, 0, stream>>>(h1, w2t, supT);
    // 4) out = A @ sup2 + b2 -> d_out (fp32)
    k_spmm_mfma<true><<<BB * 8, 256, 0, stream>>>(row_st, csr_rc, csr_v, supT, b2, h1, out);
}

// Round 13
// 238.575 us; speedup vs baseline: 1.5657x; 1.1766x over previous
//
#include <hip/hip_runtime.h>

// Problem constants (match reference setup_inputs)
#define BB   512
#define NN   512
#define NNZ  8192
#define EMB  64
#define HID  100
#define DUMPC 512            // dump "column" for merged-away duplicates -> LDS tail

// ---------------------------------------------------------------------------
// ws layout (bytes):
//   [0)          csr_rc  int  [B*NNZ]  (row<<16|col)   16,777,216
//   [16777216)   csr_v   bf16 [B*NNZ]                   8,388,608
//   [25165824)   row_st  int  [B*513]                   1,050,624
//   [26216448)   supT    bf16 [B][16kt][112col][32k]   58,720,256   (k-tiled)
//   [84936704)   w1t     bf16 [112][64]                    14,336
//   [84951040)   w2t     bf16 [112][128]                   28,672
// h1 (bf16 [B][512][112]) lives in d_out; overwritten by final fp32 output.
// ---------------------------------------------------------------------------
#define OFF_CSR_RC  0
#define OFF_CSR_V   16777216
#define OFF_ROWST   25165824
#define OFF_SUPT    26216448
#define OFF_W1T     84936704
#define OFF_W2T     84951040

typedef __attribute__((ext_vector_type(8))) short short8;
typedef __attribute__((ext_vector_type(4))) float floatx4;

__device__ __forceinline__ unsigned short f2bf(float f) {
    unsigned u = __float_as_uint(f);
    unsigned r = (u + 0x7fffu + ((u >> 16) & 1u)) >> 16;
    return (unsigned short)r;
}

__device__ __forceinline__ short8 pack8(float4 a, float4 b) {
    short8 s;
    s[0] = (short)f2bf(a.x); s[1] = (short)f2bf(a.y);
    s[2] = (short)f2bf(a.z); s[3] = (short)f2bf(a.w);
    s[4] = (short)f2bf(b.x); s[5] = (short)f2bf(b.y);
    s[6] = (short)f2bf(b.z); s[7] = (short)f2bf(b.w);
    return s;
}

// supT k-tiled addressing: elem(b, col, k) = b*57344 + (k>>5)*3584 + col*32 + (k&31)
__device__ __forceinline__ size_t supt_addr(int batch, int col, int k) {
    return (size_t)batch * 57344 + (size_t)(k >> 5) * 3584 + (size_t)col * 32 + (k & 31);
}

// ---------------------------------------------------------------------------
// CSR build, all-LDS (verified r5-r12); block BB additionally does the weight
// prep (merged to save a launch; independent work).
// ---------------------------------------------------------------------------
__global__ __launch_bounds__(512) void k_csr_build(
    const int* __restrict__ rows, const int* __restrict__ cols,
    const float* __restrict__ vals, int* __restrict__ row_start,
    int* __restrict__ csr_rc, unsigned short* __restrict__ csr_v,
    const float* __restrict__ W1, const float* __restrict__ W2,
    unsigned short* __restrict__ w1t, unsigned short* __restrict__ w2t)
{
    __shared__ int   rl[NNZ];
    __shared__ float vl[NNZ];
    __shared__ int   cnt[NN];
    __shared__ int   sc[NN];

    const int b   = blockIdx.x;
    const int tid = threadIdx.x;       // 0..511 == NN

    if (b == BB) {                     // prep block: transposed bf16 weights
        for (int id = tid; id < 112 * 128; id += 512) {
            if (id < 112 * 64) {
                int h = id >> 6, k = id & 63;
                float f = (h < 100) ? W1[k * 100 + h] : 0.f;
                w1t[id] = f2bf(f);
            }
            int h = id >> 7, k = id & 127;
            float f = (h < 100 && k < 100) ? W2[k * 100 + h] : 0.f;
            w2t[id] = f2bf(f);
        }
        return;
    }

    const int*   rb = rows + (size_t)b * NNZ;
    const int*   cb = cols + (size_t)b * NNZ;
    const float* vb = vals + (size_t)b * NNZ;

    cnt[tid] = 0;
    __syncthreads();

    #pragma unroll
    for (int i = 0; i < NNZ / 512; ++i)
        atomicAdd(&cnt[rb[tid + i * 512]], 1);
    __syncthreads();

    const int own = cnt[tid];
    sc[tid] = own;
    __syncthreads();
    #pragma unroll
    for (int off = 1; off < NN; off <<= 1) {
        int v = (tid >= off) ? sc[tid - off] : 0;
        __syncthreads();
        sc[tid] += v;
        __syncthreads();
    }
    row_start[b * 513 + tid + 1] = sc[tid];
    if (tid == 0) row_start[b * 513] = 0;
    cnt[tid] = sc[tid] - own;
    __syncthreads();

    #pragma unroll
    for (int i = 0; i < NNZ / 512; ++i) {
        int idx = tid + i * 512;
        int   r = rb[idx];
        int   c = cb[idx];
        float v = vb[idx];
        int pos = atomicAdd(&cnt[r], 1);
        rl[pos] = (r << 16) | c;
        vl[pos] = v;
    }
    __syncthreads();

    // per-row duplicate merge (duplicates redirected to DUMPC)
    {
        const int s = sc[tid] - own;
        const int e = sc[tid];
        for (int j = s; j < e - 1; ++j) {
            int pj = rl[j];
            if ((pj & 0xffff) == DUMPC) continue;
            float add = 0.f;
            bool mod = false;
            for (int j2 = j + 1; j2 < e; ++j2) {
                if (rl[j2] == pj) {
                    add += vl[j2];
                    rl[j2] = (pj & 0xffff0000) | DUMPC;
                    mod = true;
                }
            }
            if (mod) vl[j] += add;
        }
    }
    __syncthreads();

    #pragma unroll
    for (int i = 0; i < NNZ / 512; ++i) {
        int idx = tid + i * 512;
        csr_rc[(size_t)b * NNZ + idx] = rl[idx];
        csr_v [(size_t)b * NNZ + idx] = f2bf(vl[idx]);
    }
}

// ---------------------------------------------------------------------------
// GEMM1 (MFMA): supT(k-tiled) = bf16( emb[hyper] @ W1 )^T per batch. (r12)
// ---------------------------------------------------------------------------
__global__ __launch_bounds__(256) void k_gemm1_mfma(
    const int* __restrict__ hyper, const float* __restrict__ emb,
    const unsigned short* __restrict__ w1t, unsigned short* __restrict__ supT)
{
    const int lane = threadIdx.x & 63, wave = threadIdx.x >> 6;
    const int l15 = lane & 15, g4 = lane >> 4;

    short8 bq[7][2];
    #pragma unroll
    for (int ct = 0; ct < 7; ++ct)
        #pragma unroll
        for (int kt = 0; kt < 2; ++kt)
            bq[ct][kt] = *(const short8*)(w1t + (ct * 16 + l15) * 64 + kt * 32 + g4 * 8);

    const int wsid = blockIdx.x * 4 + wave;
    #pragma unroll 2
    for (int i = 0; i < 4; ++i) {
        const int  rb   = wsid * 4 + i;
        const long base = (long)rb * 16;
        const int  rid  = hyper[base + l15];
        const float* ep = emb + (long)rid * EMB + g4 * 8;
        float4 f0 = *(const float4*)(ep);
        float4 f1 = *(const float4*)(ep + 4);
        float4 f2 = *(const float4*)(ep + 32);
        float4 f3 = *(const float4*)(ep + 36);
        short8 a0 = pack8(f0, f1);
        short8 a1 = pack8(f2, f3);

        floatx4 acc[7];
        #pragma unroll
        for (int ct = 0; ct < 7; ++ct) acc[ct] = (floatx4)0.f;
        #pragma unroll
        for (int ct = 0; ct < 7; ++ct) {
            acc[ct] = __builtin_amdgcn_mfma_f32_16x16x32_bf16(a0, bq[ct][0], acc[ct], 0, 0, 0);
            acc[ct] = __builtin_amdgcn_mfma_f32_16x16x32_bf16(a1, bq[ct][1], acc[ct], 0, 0, 0);
        }

        const int batch = rb >> 5;
        const int inrow = (rb & 31) * 16 + g4 * 4;
        #pragma unroll
        for (int ct = 0; ct < 7; ++ct) {
            int col = ct * 16 + l15;
            uint2 w;
            w.x = (unsigned)f2bf(acc[ct][0]) | ((unsigned)f2bf(acc[ct][1]) << 16);
            w.y = (unsigned)f2bf(acc[ct][2]) | ((unsigned)f2bf(acc[ct][3]) << 16);
            *(uint2*)(supT + supt_addr(batch, col, inrow)) = w;
        }
    }
}

// ---------------------------------------------------------------------------
// GEMM2 (MFMA): supT(k-tiled) = bf16( h1 @ W2 )^T, h1 bf16 [512][112]. (r12)
// ---------------------------------------------------------------------------
__global__ __launch_bounds__(256) void k_gemm2_mfma(
    const unsigned short* __restrict__ h1, const unsigned short* __restrict__ w2t,
    unsigned short* __restrict__ supT)
{
    const int lane = threadIdx.x & 63, wave = threadIdx.x >> 6;
    const int l15 = lane & 15, g4 = lane >> 4;
    const int ct0 = (wave & 1) ? 4 : 0;

    short8 bq[4][4];
    #pragma unroll
    for (int ctl = 0; ctl < 4; ++ctl) {
        int ct = ct0 + ctl;
        if (ct < 7)
            #pragma unroll
            for (int kt = 0; kt < 4; ++kt)
                bq[ctl][kt] = *(const short8*)(w2t + (ct * 16 + l15) * 128 + kt * 32 + g4 * 8);
    }

    const int wp = blockIdx.x * 2 + (wave >> 1);
    #pragma unroll 2
    for (int i = 0; i < 8; ++i) {
        const int  rb   = wp * 8 + i;
        const long base = (long)rb * 16;
        const unsigned short* rp = h1 + (size_t)(base + l15) * 112;

        short8 a[4];
        #pragma unroll
        for (int kt = 0; kt < 4; ++kt) {
            int k0 = kt * 32 + g4 * 8;
            short8 av = (short8)(short)0;
            if (k0 < 112) av = *(const short8*)(rp + k0);
            a[kt] = av;
        }

        floatx4 acc[4];
        #pragma unroll
        for (int ctl = 0; ctl < 4; ++ctl) acc[ctl] = (floatx4)0.f;
        #pragma unroll
        for (int ctl = 0; ctl < 4; ++ctl) {
            if (ct0 + ctl < 7) {
                #pragma unroll
                for (int kt = 0; kt < 4; ++kt)
                    acc[ctl] = __builtin_amdgcn_mfma_f32_16x16x32_bf16(a[kt], bq[ctl][kt], acc[ctl], 0, 0, 0);
            }
        }

        const int batch = rb >> 5;
        const int inrow = (rb & 31) * 16 + g4 * 4;
        #pragma unroll
        for (int ctl = 0; ctl < 4; ++ctl) {
            if (ct0 + ctl < 7) {
                int col = (ct0 + ctl) * 16 + l15;
                uint2 w;
                w.x = (unsigned)f2bf(acc[ctl][0]) | ((unsigned)f2bf(acc[ctl][1]) << 16);
                w.y = (unsigned)f2bf(acc[ctl][2]) | ((unsigned)f2bf(acc[ctl][3]) << 16);
                *(uint2*)(supT + supt_addr(batch, col, inrow)) = w;
            }
        }
    }
}

// ---------------------------------------------------------------------------
// SpMM + bias via dense-A MFMA, K-SPLIT 8-wave version.
// 4096 blocks x 512 threads; 64-row stripes; LDS 64KB -> 2 blocks/CU =
// 16 waves/CU = 4 waves/SIMD (2x r12's TLP). Wave (kh, ng): kh = kt-half,
// ng -> n-tiles {2ng, 2ng+1}; body = r10/r12's exact 2nt x 4m unroll-4 shape.
// K-halves accumulate partials; after the MFMA barrier A_d is dead: waves
// kh=1 dump acc to LDS (lane-stride-1, conflict-free), waves kh=0 add and
// stage C; all 512 threads copy out coalesced (fixes h1 write-amp).
// A sub-tile layout is LANE-LINEAR: elem(m,kt,r,k) at
//   m*8192 + kt*512 + (k>>3)*128 + (r&15)*8 + (k&7)
// so the MFMA ds_read is exactly byte 16*lane within each 1KB tile -> zero
// bank conflicts by construction (fixes r12's 4.5M: [r][k] put lanes at
// 64B stride = 8-way).
// ---------------------------------------------------------------------------
template<bool FINAL>
__global__ __launch_bounds__(512) void k_spmm_mfma(
    const int* __restrict__ row_st, const int* __restrict__ rc,
    const unsigned short* __restrict__ vv, const unsigned short* __restrict__ supT,
    const float* __restrict__ bias, unsigned short* __restrict__ h1,
    float* __restrict__ out)
{
    __shared__ unsigned short Ad[64 * 512 + 64];  // 65,664 B -> 2 blocks/CU

    const int tid    = threadIdx.x;
    // XCD-locality swizzle (8 XCDs, round-robin blockIdx%8 -> XCD)
    const int xcd    = blockIdx.x & 7;
    const int local  = blockIdx.x >> 3;          // 0..511
    const int batch  = xcd * 64 + (local >> 3);
    const int stripe = local & 7;
    const int r0     = stripe * 64;

    // P0: issue CSR loads EARLY (use-late after the zero phase)
    const int s0 = row_st[batch * 513 + r0];
    const int e0 = row_st[batch * 513 + r0 + 64];
    const int*            rcb = rc + (size_t)batch * NNZ;
    const unsigned short* vvb = vv + (size_t)batch * NNZ;
    int            pc[3];
    unsigned short pv[3];
    #pragma unroll
    for (int i = 0; i < 3; ++i) {
        int idx = s0 + tid + i * 512;
        bool ok = idx < e0;
        pc[i] = ok ? rcb[idx] : 0;
        pv[i] = ok ? vvb[idx] : 0;
    }

    // P1: zero A_d (4104 uint4)
    {
        uint4* z = (uint4*)Ad;
        #pragma unroll
        for (int i = 0; i < 9; ++i) {
            int idx = tid + i * 512;
            if (idx < 4104) z[idx] = make_uint4(0u, 0u, 0u, 0u);
        }
    }
    __syncthreads();

    // P2: scatter from regs; lane-linear sub-tile addressing.
    #pragma unroll
    for (int i = 0; i < 3; ++i) {
        int idx = s0 + tid + i * 512;
        if (idx < e0) {
            int r = ((pc[i] >> 16) & 0xffff) - r0;
            int c = pc[i] & 0xffff;
            int a = (c < 512)
                ? ((r >> 4) * 8192 + (c >> 5) * 512 + ((c >> 3) & 3) * 128 + (r & 15) * 8 + (c & 7))
                : (64 * 512 + (tid & 63));
            Ad[a] = pv[i];
        }
    }
    // overflow fallback (cnt > 1536: statistically never, correctness only)
    for (int idx = s0 + 1536 + tid; idx < e0; idx += 512) {
        int p = rcb[idx];
        int r = ((p >> 16) & 0xffff) - r0;
        int c = p & 0xffff;
        int a = (c < 512)
            ? ((r >> 4) * 8192 + (c >> 5) * 512 + ((c >> 3) & 3) * 128 + (r & 15) * 8 + (c & 7))
            : (64 * 512 + (tid & 63));
        Ad[a] = vvb[idx];
    }
    __syncthreads();

    // P3: MFMA — wave (kh, ng): kt in [kh*8, kh*8+8), n-tiles {2ng, 2ng+1}
    const int lane = tid & 63, wave = tid >> 6;
    const int l15 = lane & 15, g4 = lane >> 4;
    const int ng  = wave & 3, kh = wave >> 2;
    const int nt0 = ng * 2;
    const bool two = (nt0 + 1) < 7;              // ng=3 owns only n-tile 6
    const int ktb = kh * 8;

    const unsigned short* b0p = supT + (size_t)batch * 57344 + (size_t)ktb * 3584
                               + (nt0 * 16 + l15) * 32 + g4 * 8;
    const unsigned short* b1p = b0p + 512;       // next n-tile
    const unsigned short* ap  = Ad + (size_t)ktb * 512 + lane * 8;  // lane-linear

    floatx4 acc[2][4];
    #pragma unroll
    for (int n = 0; n < 2; ++n)
        #pragma unroll
        for (int m = 0; m < 4; ++m) acc[n][m] = (floatx4)0.f;

    #pragma unroll 4
    for (int kt = 0; kt < 8; ++kt) {
        short8 b0 = *(const short8*)(b0p + (size_t)kt * 3584);
        short8 b1 = (short8)(short)0;
        if (two) b1 = *(const short8*)(b1p + (size_t)kt * 3584);
        #pragma unroll
        for (int m = 0; m < 4; ++m) {
            short8 a = *(const short8*)(ap + m * 8192 + kt * 512);
            acc[0][m] = __builtin_amdgcn_mfma_f32_16x16x32_bf16(a, b0, acc[0][m], 0, 0, 0);
            if (two)
                acc[1][m] = __builtin_amdgcn_mfma_f32_16x16x32_bf16(a, b1, acc[1][m], 0, 0, 0);
        }
    }
    __syncthreads();                             // all MFMAs done; A_d dead

    // P4: k-half reduction through LDS. redu[slot:4][i:32][lane:64] f32 (32KB)
    float* redu = (float*)Ad;
    if (kh == 1) {
        #pragma unroll
        for (int nn = 0; nn < 2; ++nn)
            #pragma unroll
            for (int m = 0; m < 4; ++m)
                #pragma unroll
                for (int q = 0; q < 4; ++q)
                    redu[ng * 2048 + ((nn * 4 + m) * 4 + q) * 64 + lane] = acc[nn][m][q];
    }
    __syncthreads();

    // P5: waves kh=0 add partner partials and stage C (+bias) at byte 32768
    if (kh == 0) {
        #pragma unroll
        for (int nn = 0; nn < 2; ++nn)
            #pragma unroll
            for (int m = 0; m < 4; ++m)
                #pragma unroll
                for (int q = 0; q < 4; ++q)
                    acc[nn][m][q] += redu[ng * 2048 + ((nn * 4 + m) * 4 + q) * 64 + lane];

        if (FINAL) {
            float* st = (float*)((char*)Ad + 32768);           // [64][112] f32
            #pragma unroll
            for (int nn = 0; nn < 2; ++nn) {
                int nt = nt0 + nn;
                if (nt >= 7) break;
                int col = nt * 16 + l15;
                float bi = (col < HID) ? bias[col] : 0.f;
                #pragma unroll
                for (int m = 0; m < 4; ++m) {
                    int row = m * 16 + g4 * 4;
                    #pragma unroll
                    for (int q = 0; q < 4; ++q)
                        st[(row + q) * 112 + col] = acc[nn][m][q] + bi;
                }
            }
        } else {
            unsigned short* st = (unsigned short*)((char*)Ad + 32768);  // [64][112] bf16
            #pragma unroll
            for (int nn = 0; nn < 2; ++nn) {
                int nt = nt0 + nn;
                if (nt >= 7) break;
                int col = nt * 16 + l15;
                float bi = (col < HID) ? bias[col] : 0.f;      // pad cols: acc==0 -> 0
                #pragma unroll
                for (int m = 0; m < 4; ++m) {
                    int row = m * 16 + g4 * 4;
                    #pragma unroll
                    for (int q = 0; q < 4; ++q)
                        st[(row + q) * 112 + col] = f2bf(acc[nn][m][q] + bi);
                }
            }
        }
    }
    __syncthreads();

    // P6: coalesced copy-out, all 512 threads
    if (FINAL) {
        const float* st = (const float*)((char*)Ad + 32768);
        #pragma unroll
        for (int i = 0; i < 4; ++i) {
            int flat = tid + i * 512;
            if (flat < 1600) {                   // 64 rows x 25 float4
                int row = flat / 25, wi = flat - row * 25;
                float4 v = *(const float4*)(st + row * 112 + wi * 4);
                *(float4*)(out + ((size_t)batch * NN + r0 + row) * HID + wi * 4) = v;
            }
        }
    } else {
        const unsigned short* st = (const unsigned short*)((char*)Ad + 32768);
        #pragma unroll
        for (int i = 0; i < 2; ++i) {
            int flat = tid + i * 512;
            if (flat < 896) {                    // 64 rows x 14 uint4
                int row = flat / 14, wi = flat - row * 14;
                uint4 v = *(const uint4*)(st + row * 112 + wi * 8);
                *(uint4*)(h1 + ((size_t)batch * NN + r0 + row) * 112 + wi * 8) = v;
            }
        }
    }
}

// ---------------------------------------------------------------------------
extern "C" void kernel_launch(void* const* d_in, const int* in_sizes, int n_in,
                              void* d_out, int out_size, void* d_ws, size_t ws_size,
                              hipStream_t stream)
{
    const int*   hyper = (const int*)  d_in[0];
    const int*   arows = (const int*)  d_in[1];
    const int*   acols = (const int*)  d_in[2];
    const float* avals = (const float*)d_in[3];
    const float* emb   = (const float*)d_in[4];
    const float* W1    = (const float*)d_in[5];
    const float* b1    = (const float*)d_in[6];
    const float* W2    = (const float*)d_in[7];
    const float* b2    = (const float*)d_in[8];

    float*          out = (float*)d_out;
    unsigned short* h1  = (unsigned short*)d_out;   // bf16 [B][512][112] view
    char*           ws  = (char*)d_ws;

    int*            csr_rc = (int*)           (ws + OFF_CSR_RC);
    unsigned short* csr_v  = (unsigned short*)(ws + OFF_CSR_V);
    int*            row_st = (int*)           (ws + OFF_ROWST);
    unsigned short* supT   = (unsigned short*)(ws + OFF_SUPT);
    unsigned short* w1t    = (unsigned short*)(ws + OFF_W1T);
    unsigned short* w2t    = (unsigned short*)(ws + OFF_W2T);

    // CSR build + weight prep (merged; A shared by both layers)
    k_csr_build<<<BB + 1, 512, 0, stream>>>(arows, acols, avals, row_st,
                                            csr_rc, csr_v, W1, W2, w1t, w2t);

    // 1) supT(k-tiled) = bf16(emb[hyper] @ W1)^T (per batch)
    k_gemm1_mfma<<<1024, 256, 0, stream>>>(hyper, emb, w1t, supT);
    // 2) h1 = bf16(A @ sup1 + b1) -> d_out (bf16 [512][112])
    k_spmm_mfma<false><<<BB * 8, 512, 0, stream>>>(row_st, csr_rc, csr_v, supT, b1, h1, out);
    // 3) supT(k-tiled) = bf16(h1 @ W2)^T (per batch)
    k_gemm2_mfma<<<1024, 256, 0, stream>>>(h1, w2t, supT);
    // 4) out = A @ sup2 + b2 -> d_out (fp32)
    k_spmm_mfma<true><<<BB * 8, 512, 0, stream>>>(row_st, csr_rc, csr_v, supT, b2, h1, out);
}

// Round 14
// 216.543 us; speedup vs baseline: 1.7250x; 1.1017x over previous
//
#include <hip/hip_runtime.h>

// Problem constants (match reference setup_inputs)
#define BB   512
#define NN   512
#define NNZ  8192
#define EMB  64
#define HID  100
#define DUMPC 512            // dump "column" for dup placeholders -> LDS tail in spmm
#define EXCAP 1024           // exception-list capacity (mean ~128, 80-sigma margin)

// ---------------------------------------------------------------------------
// ws layout (bytes):
//   [0)          csr_rc  int  [B*NNZ]  (row<<16|col)   16,777,216
//   [16777216)   csr_v   bf16 [B*NNZ]                   8,388,608
//   [25165824)   row_st  int  [B*513]                   1,050,624
//   [26216448)   supT    bf16 [B][16kt][112col][32k]   58,720,256   (k-tiled)
//   [84936704)   w1t     bf16 [112][64]                    14,336
//   [84951040)   w2t     bf16 [112][128]                   28,672
// h1 (bf16 [B][512][112]) lives in d_out; overwritten by final fp32 output.
// ---------------------------------------------------------------------------
#define OFF_CSR_RC  0
#define OFF_CSR_V   16777216
#define OFF_ROWST   25165824
#define OFF_SUPT    26216448
#define OFF_W1T     84936704
#define OFF_W2T     84951040

typedef __attribute__((ext_vector_type(8))) short short8;
typedef __attribute__((ext_vector_type(4))) float floatx4;

__device__ __forceinline__ unsigned short f2bf(float f) {
    unsigned u = __float_as_uint(f);
    unsigned r = (u + 0x7fffu + ((u >> 16) & 1u)) >> 16;
    return (unsigned short)r;
}

__device__ __forceinline__ short8 pack8(float4 a, float4 b) {
    short8 s;
    s[0] = (short)f2bf(a.x); s[1] = (short)f2bf(a.y);
    s[2] = (short)f2bf(a.z); s[3] = (short)f2bf(a.w);
    s[4] = (short)f2bf(b.x); s[5] = (short)f2bf(b.y);
    s[6] = (short)f2bf(b.z); s[7] = (short)f2bf(b.w);
    return s;
}

// supT k-tiled addressing: elem(b, col, k) = b*57344 + (k>>5)*3584 + col*32 + (k&31)
__device__ __forceinline__ size_t supt_addr(int batch, int col, int k) {
    return (size_t)batch * 57344 + (size_t)(k >> 5) * 3584 + (size_t)col * 32 + (k & 31);
}

// ---------------------------------------------------------------------------
// CSR build v2: bitmap duplicate detection (O(k) instead of O(k^2) serial).
//   P1 histogram -> P2 wave-shuffle scan (2 barriers, was 18) ->
//   P3 scatter + atomicOr on a 512x512-bit LDS bitmap: losers become DUMPC
//      placeholders + push (key,v) to a small exception list ->
//   P4 parallel exception resolve: scan own row segment (~16), f32 atomicAdd
//      onto the canonical entry (multi-dup safe) ->
//   P5 coalesced writeback (f2bf once, numerics identical to r5-r13 merge).
// LDS ~110 KB -> 1 block/CU; per-block critical path is now all O(nnz/512).
// Block 0 does the weight prep (tiny); batches are blockIdx-1.
// ---------------------------------------------------------------------------
__global__ __launch_bounds__(512) void k_csr_build(
    const int* __restrict__ rows, const int* __restrict__ cols,
    const float* __restrict__ vals, int* __restrict__ row_start,
    int* __restrict__ csr_rc, unsigned short* __restrict__ csr_v,
    const float* __restrict__ W1, const float* __restrict__ W2,
    unsigned short* __restrict__ w1t, unsigned short* __restrict__ w2t)
{
    __shared__ int      rl[NNZ];          // 32 KB  (r<<16)|c after scatter
    __shared__ float    vl[NNZ];          // 32 KB  values (f32 until writeback)
    __shared__ unsigned bmap[NN * 16];    // 32 KB  512x512 bits
    __shared__ int      cnt[NN];          // 2 KB   histogram -> cursor
    __shared__ int      sc[NN];           // 2 KB   inclusive scan (persists)
    __shared__ int      exc_rc[EXCAP];    // 4 KB
    __shared__ float    exc_v[EXCAP];     // 4 KB
    __shared__ int      wsum[8], woff[8], nexc;

    const int tid = threadIdx.x;          // 0..511 == NN

    if (blockIdx.x == 0) {                // prep block: transposed bf16 weights
        for (int id = tid; id < 112 * 128; id += 512) {
            if (id < 112 * 64) {
                int h = id >> 6, k = id & 63;
                float f = (h < 100) ? W1[k * 100 + h] : 0.f;
                w1t[id] = f2bf(f);
            }
            int h = id >> 7, k = id & 127;
            float f = (h < 100 && k < 100) ? W2[k * 100 + h] : 0.f;
            w2t[id] = f2bf(f);
        }
        return;
    }
    const int b = blockIdx.x - 1;

    const int*   rb = rows + (size_t)b * NNZ;
    const int*   cb = cols + (size_t)b * NNZ;
    const float* vb = vals + (size_t)b * NNZ;

    cnt[tid] = 0;
    #pragma unroll
    for (int i = 0; i < 16; ++i) bmap[tid + i * 512] = 0u;
    if (tid == 0) nexc = 0;
    __syncthreads();

    // P1: histogram
    #pragma unroll
    for (int i = 0; i < NNZ / 512; ++i)
        atomicAdd(&cnt[rb[tid + i * 512]], 1);
    __syncthreads();

    // P2: scan via wave shuffles (2 barriers)
    const int lane = tid & 63, wid = tid >> 6;
    const int own = cnt[tid];
    int x = own;
    #pragma unroll
    for (int off = 1; off < 64; off <<= 1) {
        int y = __shfl_up(x, off);
        if (lane >= off) x += y;
    }
    if (lane == 63) wsum[wid] = x;
    __syncthreads();
    if (tid == 0) {
        int a = 0;
        #pragma unroll
        for (int w = 0; w < 8; ++w) { woff[w] = a; a += wsum[w]; }
    }
    __syncthreads();
    x += woff[wid];                        // inclusive scan over 512
    sc[tid] = x;
    row_start[b * 513 + tid + 1] = x;
    if (tid == 0) row_start[b * 513] = 0;
    cnt[tid] = x - own;                    // exclusive cursor
    __syncthreads();

    // P3: scatter + bitmap dup detection
    #pragma unroll
    for (int i = 0; i < NNZ / 512; ++i) {
        int idx = tid + i * 512;
        int   r = rb[idx];
        int   c = cb[idx];
        float v = vb[idx];
        unsigned bit = 1u << (c & 31);
        unsigned old = atomicOr(&bmap[(r << 4) + (c >> 5)], bit);
        int pos = atomicAdd(&cnt[r], 1);
        bool dup = (old & bit) != 0;
        int e = -1;
        if (dup) e = atomicAdd(&nexc, 1);
        if (dup && e < EXCAP) {
            rl[pos] = (r << 16) | DUMPC;   // placeholder keeps slots consistent
            vl[pos] = 0.f;
            exc_rc[e] = (r << 16) | c;
            exc_v[e]  = v;
        } else {                            // normal entry (or impossible overflow)
            rl[pos] = (r << 16) | c;
            vl[pos] = v;
        }
    }
    __syncthreads();

    // P4: parallel exception resolve (row segments ~16; atomicAdd = multi-dup safe)
    {
        int ne = nexc < EXCAP ? nexc : EXCAP;
        for (int t = tid; t < ne; t += 512) {
            int key = exc_rc[t];
            int r   = key >> 16;
            int lo  = r ? sc[r - 1] : 0;
            int hi  = sc[r];
            for (int j = lo; j < hi; ++j) {
                if (rl[j] == key) { atomicAdd(&vl[j], exc_v[t]); break; }
            }
        }
    }
    __syncthreads();

    // P5: coalesced writeback
    #pragma unroll
    for (int i = 0; i < NNZ / 512; ++i) {
        int idx = tid + i * 512;
        csr_rc[(size_t)b * NNZ + idx] = rl[idx];
        csr_v [(size_t)b * NNZ + idx] = f2bf(vl[idx]);
    }
}

// ---------------------------------------------------------------------------
// GEMM1 (MFMA): supT(k-tiled) = bf16( emb[hyper] @ W1 )^T per batch. (r12/r13)
// ---------------------------------------------------------------------------
__global__ __launch_bounds__(256) void k_gemm1_mfma(
    const int* __restrict__ hyper, const float* __restrict__ emb,
    const unsigned short* __restrict__ w1t, unsigned short* __restrict__ supT)
{
    const int lane = threadIdx.x & 63, wave = threadIdx.x >> 6;
    const int l15 = lane & 15, g4 = lane >> 4;

    short8 bq[7][2];
    #pragma unroll
    for (int ct = 0; ct < 7; ++ct)
        #pragma unroll
        for (int kt = 0; kt < 2; ++kt)
            bq[ct][kt] = *(const short8*)(w1t + (ct * 16 + l15) * 64 + kt * 32 + g4 * 8);

    const int wsid = blockIdx.x * 4 + wave;
    #pragma unroll 2
    for (int i = 0; i < 4; ++i) {
        const int  rb   = wsid * 4 + i;
        const long base = (long)rb * 16;
        const int  rid  = hyper[base + l15];
        const float* ep = emb + (long)rid * EMB + g4 * 8;
        float4 f0 = *(const float4*)(ep);
        float4 f1 = *(const float4*)(ep + 4);
        float4 f2 = *(const float4*)(ep + 32);
        float4 f3 = *(const float4*)(ep + 36);
        short8 a0 = pack8(f0, f1);
        short8 a1 = pack8(f2, f3);

        floatx4 acc[7];
        #pragma unroll
        for (int ct = 0; ct < 7; ++ct) acc[ct] = (floatx4)0.f;
        #pragma unroll
        for (int ct = 0; ct < 7; ++ct) {
            acc[ct] = __builtin_amdgcn_mfma_f32_16x16x32_bf16(a0, bq[ct][0], acc[ct], 0, 0, 0);
            acc[ct] = __builtin_amdgcn_mfma_f32_16x16x32_bf16(a1, bq[ct][1], acc[ct], 0, 0, 0);
        }

        const int batch = rb >> 5;
        const int inrow = (rb & 31) * 16 + g4 * 4;
        #pragma unroll
        for (int ct = 0; ct < 7; ++ct) {
            int col = ct * 16 + l15;
            uint2 w;
            w.x = (unsigned)f2bf(acc[ct][0]) | ((unsigned)f2bf(acc[ct][1]) << 16);
            w.y = (unsigned)f2bf(acc[ct][2]) | ((unsigned)f2bf(acc[ct][3]) << 16);
            *(uint2*)(supT + supt_addr(batch, col, inrow)) = w;
        }
    }
}

// ---------------------------------------------------------------------------
// GEMM2 (MFMA): supT(k-tiled) = bf16( h1 @ W2 )^T, h1 bf16 [512][112]. (r12/r13)
// ---------------------------------------------------------------------------
__global__ __launch_bounds__(256) void k_gemm2_mfma(
    const unsigned short* __restrict__ h1, const unsigned short* __restrict__ w2t,
    unsigned short* __restrict__ supT)
{
    const int lane = threadIdx.x & 63, wave = threadIdx.x >> 6;
    const int l15 = lane & 15, g4 = lane >> 4;
    const int ct0 = (wave & 1) ? 4 : 0;

    short8 bq[4][4];
    #pragma unroll
    for (int ctl = 0; ctl < 4; ++ctl) {
        int ct = ct0 + ctl;
        if (ct < 7)
            #pragma unroll
            for (int kt = 0; kt < 4; ++kt)
                bq[ctl][kt] = *(const short8*)(w2t + (ct * 16 + l15) * 128 + kt * 32 + g4 * 8);
    }

    const int wp = blockIdx.x * 2 + (wave >> 1);
    #pragma unroll 2
    for (int i = 0; i < 8; ++i) {
        const int  rb   = wp * 8 + i;
        const long base = (long)rb * 16;
        const unsigned short* rp = h1 + (size_t)(base + l15) * 112;

        short8 a[4];
        #pragma unroll
        for (int kt = 0; kt < 4; ++kt) {
            int k0 = kt * 32 + g4 * 8;
            short8 av = (short8)(short)0;
            if (k0 < 112) av = *(const short8*)(rp + k0);
            a[kt] = av;
        }

        floatx4 acc[4];
        #pragma unroll
        for (int ctl = 0; ctl < 4; ++ctl) acc[ctl] = (floatx4)0.f;
        #pragma unroll
        for (int ctl = 0; ctl < 4; ++ctl) {
            if (ct0 + ctl < 7) {
                #pragma unroll
                for (int kt = 0; kt < 4; ++kt)
                    acc[ctl] = __builtin_amdgcn_mfma_f32_16x16x32_bf16(a[kt], bq[ctl][kt], acc[ctl], 0, 0, 0);
            }
        }

        const int batch = rb >> 5;
        const int inrow = (rb & 31) * 16 + g4 * 4;
        #pragma unroll
        for (int ctl = 0; ctl < 4; ++ctl) {
            if (ct0 + ctl < 7) {
                int col = (ct0 + ctl) * 16 + l15;
                uint2 w;
                w.x = (unsigned)f2bf(acc[ctl][0]) | ((unsigned)f2bf(acc[ctl][1]) << 16);
                w.y = (unsigned)f2bf(acc[ctl][2]) | ((unsigned)f2bf(acc[ctl][3]) << 16);
                *(uint2*)(supT + supt_addr(batch, col, inrow)) = w;
            }
        }
    }
}

// ---------------------------------------------------------------------------
// SpMM + bias via dense-A MFMA, K-SPLIT 8-wave version (verified r13, unchanged).
// ---------------------------------------------------------------------------
template<bool FINAL>
__global__ __launch_bounds__(512) void k_spmm_mfma(
    const int* __restrict__ row_st, const int* __restrict__ rc,
    const unsigned short* __restrict__ vv, const unsigned short* __restrict__ supT,
    const float* __restrict__ bias, unsigned short* __restrict__ h1,
    float* __restrict__ out)
{
    __shared__ unsigned short Ad[64 * 512 + 64];  // 65,664 B -> 2 blocks/CU

    const int tid    = threadIdx.x;
    // XCD-locality swizzle (8 XCDs, round-robin blockIdx%8 -> XCD)
    const int xcd    = blockIdx.x & 7;
    const int local  = blockIdx.x >> 3;          // 0..511
    const int batch  = xcd * 64 + (local >> 3);
    const int stripe = local & 7;
    const int r0     = stripe * 64;

    // P0: issue CSR loads EARLY (use-late after the zero phase)
    const int s0 = row_st[batch * 513 + r0];
    const int e0 = row_st[batch * 513 + r0 + 64];
    const int*            rcb = rc + (size_t)batch * NNZ;
    const unsigned short* vvb = vv + (size_t)batch * NNZ;
    int            pc[3];
    unsigned short pv[3];
    #pragma unroll
    for (int i = 0; i < 3; ++i) {
        int idx = s0 + tid + i * 512;
        bool ok = idx < e0;
        pc[i] = ok ? rcb[idx] : 0;
        pv[i] = ok ? vvb[idx] : 0;
    }

    // P1: zero A_d (4104 uint4)
    {
        uint4* z = (uint4*)Ad;
        #pragma unroll
        for (int i = 0; i < 9; ++i) {
            int idx = tid + i * 512;
            if (idx < 4104) z[idx] = make_uint4(0u, 0u, 0u, 0u);
        }
    }
    __syncthreads();

    // P2: scatter from regs; lane-linear sub-tile addressing.
    #pragma unroll
    for (int i = 0; i < 3; ++i) {
        int idx = s0 + tid + i * 512;
        if (idx < e0) {
            int r = ((pc[i] >> 16) & 0xffff) - r0;
            int c = pc[i] & 0xffff;
            int a = (c < 512)
                ? ((r >> 4) * 8192 + (c >> 5) * 512 + ((c >> 3) & 3) * 128 + (r & 15) * 8 + (c & 7))
                : (64 * 512 + (tid & 63));
            Ad[a] = pv[i];
        }
    }
    // overflow fallback (cnt > 1536: statistically never, correctness only)
    for (int idx = s0 + 1536 + tid; idx < e0; idx += 512) {
        int p = rcb[idx];
        int r = ((p >> 16) & 0xffff) - r0;
        int c = p & 0xffff;
        int a = (c < 512)
            ? ((r >> 4) * 8192 + (c >> 5) * 512 + ((c >> 3) & 3) * 128 + (r & 15) * 8 + (c & 7))
            : (64 * 512 + (tid & 63));
        Ad[a] = vvb[idx];
    }
    __syncthreads();

    // P3: MFMA — wave (kh, ng): kt in [kh*8, kh*8+8), n-tiles {2ng, 2ng+1}
    const int lane = tid & 63, wave = tid >> 6;
    const int l15 = lane & 15, g4 = lane >> 4;
    const int ng  = wave & 3, kh = wave >> 2;
    const int nt0 = ng * 2;
    const bool two = (nt0 + 1) < 7;              // ng=3 owns only n-tile 6
    const int ktb = kh * 8;

    const unsigned short* b0p = supT + (size_t)batch * 57344 + (size_t)ktb * 3584
                               + (nt0 * 16 + l15) * 32 + g4 * 8;
    const unsigned short* b1p = b0p + 512;       // next n-tile
    const unsigned short* ap  = Ad + (size_t)ktb * 512 + lane * 8;  // lane-linear

    floatx4 acc[2][4];
    #pragma unroll
    for (int n = 0; n < 2; ++n)
        #pragma unroll
        for (int m = 0; m < 4; ++m) acc[n][m] = (floatx4)0.f;

    #pragma unroll 4
    for (int kt = 0; kt < 8; ++kt) {
        short8 b0 = *(const short8*)(b0p + (size_t)kt * 3584);
        short8 b1 = (short8)(short)0;
        if (two) b1 = *(const short8*)(b1p + (size_t)kt * 3584);
        #pragma unroll
        for (int m = 0; m < 4; ++m) {
            short8 a = *(const short8*)(ap + m * 8192 + kt * 512);
            acc[0][m] = __builtin_amdgcn_mfma_f32_16x16x32_bf16(a, b0, acc[0][m], 0, 0, 0);
            if (two)
                acc[1][m] = __builtin_amdgcn_mfma_f32_16x16x32_bf16(a, b1, acc[1][m], 0, 0, 0);
        }
    }
    __syncthreads();                             // all MFMAs done; A_d dead

    // P4: k-half reduction through LDS. redu[slot:4][i:32][lane:64] f32 (32KB)
    float* redu = (float*)Ad;
    if (kh == 1) {
        #pragma unroll
        for (int nn = 0; nn < 2; ++nn)
            #pragma unroll
            for (int m = 0; m < 4; ++m)
                #pragma unroll
                for (int q = 0; q < 4; ++q)
                    redu[ng * 2048 + ((nn * 4 + m) * 4 + q) * 64 + lane] = acc[nn][m][q];
    }
    __syncthreads();

    // P5: waves kh=0 add partner partials and stage C (+bias) at byte 32768
    if (kh == 0) {
        #pragma unroll
        for (int nn = 0; nn < 2; ++nn)
            #pragma unroll
            for (int m = 0; m < 4; ++m)
                #pragma unroll
                for (int q = 0; q < 4; ++q)
                    acc[nn][m][q] += redu[ng * 2048 + ((nn * 4 + m) * 4 + q) * 64 + lane];

        if (FINAL) {
            float* st = (float*)((char*)Ad + 32768);           // [64][112] f32
            #pragma unroll
            for (int nn = 0; nn < 2; ++nn) {
                int nt = nt0 + nn;
                if (nt >= 7) break;
                int col = nt * 16 + l15;
                float bi = (col < HID) ? bias[col] : 0.f;
                #pragma unroll
                for (int m = 0; m < 4; ++m) {
                    int row = m * 16 + g4 * 4;
                    #pragma unroll
                    for (int q = 0; q < 4; ++q)
                        st[(row + q) * 112 + col] = acc[nn][m][q] + bi;
                }
            }
        } else {
            unsigned short* st = (unsigned short*)((char*)Ad + 32768);  // [64][112] bf16
            #pragma unroll
            for (int nn = 0; nn < 2; ++nn) {
                int nt = nt0 + nn;
                if (nt >= 7) break;
                int col = nt * 16 + l15;
                float bi = (col < HID) ? bias[col] : 0.f;      // pad cols: acc==0 -> 0
                #pragma unroll
                for (int m = 0; m < 4; ++m) {
                    int row = m * 16 + g4 * 4;
                    #pragma unroll
                    for (int q = 0; q < 4; ++q)
                        st[(row + q) * 112 + col] = f2bf(acc[nn][m][q] + bi);
                }
            }
        }
    }
    __syncthreads();

    // P6: coalesced copy-out, all 512 threads
    if (FINAL) {
        const float* st = (const float*)((char*)Ad + 32768);
        #pragma unroll
        for (int i = 0; i < 4; ++i) {
            int flat = tid + i * 512;
            if (flat < 1600) {                   // 64 rows x 25 float4
                int row = flat / 25, wi = flat - row * 25;
                float4 v = *(const float4*)(st + row * 112 + wi * 4);
                *(float4*)(out + ((size_t)batch * NN + r0 + row) * HID + wi * 4) = v;
            }
        }
    } else {
        const unsigned short* st = (const unsigned short*)((char*)Ad + 32768);
        #pragma unroll
        for (int i = 0; i < 2; ++i) {
            int flat = tid + i * 512;
            if (flat < 896) {                    // 64 rows x 14 uint4
                int row = flat / 14, wi = flat - row * 14;
                uint4 v = *(const uint4*)(st + row * 112 + wi * 8);
                *(uint4*)(h1 + ((size_t)batch * NN + r0 + row) * 112 + wi * 8) = v;
            }
        }
    }
}

// ---------------------------------------------------------------------------
extern "C" void kernel_launch(void* const* d_in, const int* in_sizes, int n_in,
                              void* d_out, int out_size, void* d_ws, size_t ws_size,
                              hipStream_t stream)
{
    const int*   hyper = (const int*)  d_in[0];
    const int*   arows = (const int*)  d_in[1];
    const int*   acols = (const int*)  d_in[2];
    const float* avals = (const float*)d_in[3];
    const float* emb   = (const float*)d_in[4];
    const float* W1    = (const float*)d_in[5];
    const float* b1    = (const float*)d_in[6];
    const float* W2    = (const float*)d_in[7];
    const float* b2    = (const float*)d_in[8];

    float*          out = (float*)d_out;
    unsigned short* h1  = (unsigned short*)d_out;   // bf16 [B][512][112] view
    char*           ws  = (char*)d_ws;

    int*            csr_rc = (int*)           (ws + OFF_CSR_RC);
    unsigned short* csr_v  = (unsigned short*)(ws + OFF_CSR_V);
    int*            row_st = (int*)           (ws + OFF_ROWST);
    unsigned short* supT   = (unsigned short*)(ws + OFF_SUPT);
    unsigned short* w1t    = (unsigned short*)(ws + OFF_W1T);
    unsigned short* w2t    = (unsigned short*)(ws + OFF_W2T);

    // CSR build v2 (bitmap dup-merge) + weight prep (block 0)
    k_csr_build<<<BB + 1, 512, 0, stream>>>(arows, acols, avals, row_st,
                                            csr_rc, csr_v, W1, W2, w1t, w2t);

    // 1) supT(k-tiled) = bf16(emb[hyper] @ W1)^T (per batch)
    k_gemm1_mfma<<<1024, 256, 0, stream>>>(hyper, emb, w1t, supT);
    // 2) h1 = bf16(A @ sup1 + b1) -> d_out (bf16 [512][112])
    k_spmm_mfma<false><<<BB * 8, 512, 0, stream>>>(row_st, csr_rc, csr_v, supT, b1, h1, out);
    // 3) supT(k-tiled) = bf16(h1 @ W2)^T (per batch)
    k_gemm2_mfma<<<1024, 256, 0, stream>>>(h1, w2t, supT);
    // 4) out = A @ sup2 + b2 -> d_out (fp32)
    k_spmm_mfma<true><<<BB * 8, 512, 0, stream>>>(row_st, csr_rc, csr_v, supT, b2, h1, out);
}

// Round 15
// 207.012 us; speedup vs baseline: 1.8044x; 1.0460x over previous
//
#include <hip/hip_runtime.h>

// Problem constants (match reference setup_inputs)
#define BB   512
#define NN   512
#define NNZ  8192
#define EMB  64
#define HID  100
#define DUMPC 512            // dump "column" for dup placeholders -> LDS tail in spmm
#define EXCAP 1024           // exception-list capacity (mean ~128, 80-sigma margin)

// ---------------------------------------------------------------------------
// ws layout (bytes):
//   [0)          csr_rc  int  [B*NNZ]  (row<<16|col)   16,777,216
//   [16777216)   csr_v   bf16 [B*NNZ]                   8,388,608
//   [25165824)   row_st  int  [B*513]                   1,050,624
//   [26216448)   supT    bf16 [B][16kt][112col][32k]   58,720,256   (k-tiled)
//   [84936704)   w1t     bf16 [112][64]                    14,336
//   [84951040)   w2t     bf16 [112][128]                   28,672
// h1 (bf16 [B][512][112]) lives in d_out; overwritten by final fp32 output.
// ---------------------------------------------------------------------------
#define OFF_CSR_RC  0
#define OFF_CSR_V   16777216
#define OFF_ROWST   25165824
#define OFF_SUPT    26216448
#define OFF_W1T     84936704
#define OFF_W2T     84951040

typedef __attribute__((ext_vector_type(8))) short short8;
typedef __attribute__((ext_vector_type(4))) float floatx4;

__device__ __forceinline__ unsigned short f2bf(float f) {
    unsigned u = __float_as_uint(f);
    unsigned r = (u + 0x7fffu + ((u >> 16) & 1u)) >> 16;
    return (unsigned short)r;
}

__device__ __forceinline__ short8 pack8(float4 a, float4 b) {
    short8 s;
    s[0] = (short)f2bf(a.x); s[1] = (short)f2bf(a.y);
    s[2] = (short)f2bf(a.z); s[3] = (short)f2bf(a.w);
    s[4] = (short)f2bf(b.x); s[5] = (short)f2bf(b.y);
    s[6] = (short)f2bf(b.z); s[7] = (short)f2bf(b.w);
    return s;
}

// supT k-tiled addressing: elem(b, col, k) = b*57344 + (k>>5)*3584 + col*32 + (k&31)
__device__ __forceinline__ size_t supt_addr(int batch, int col, int k) {
    return (size_t)batch * 57344 + (size_t)(k >> 5) * 3584 + (size_t)col * 32 + (k & 31);
}

// ---------------------------------------------------------------------------
// CSR build v3: one co-resident round.
//  - LDS ~78 KB (<80) -> 2 blocks/CU; grid EXACTLY 512 blocks -> 1 round.
//    (r14 was 111 KB + 513 blocks -> 1/CU x 2 rounds; that was the cost.)
//  - rl[] dropped: csr_rc written directly to global in P3 (private 32 KB
//    window, L2-resident, written back once — r5-proven). P4 searches that
//    segment (same-block visibility via __syncthreads fence; L1-hot).
//  - rows[] loaded ONCE into 16 registers (was read in P1 and P3).
//  - weight prep striped across blocks (threads 0..41, 1 elem each).
// Numerics identical: dups summed in f32 (LDS atomicAdd), one f2bf at end.
// ---------------------------------------------------------------------------
__global__ __launch_bounds__(512) void k_csr_build(
    const int* __restrict__ rows, const int* __restrict__ cols,
    const float* __restrict__ vals, int* __restrict__ row_start,
    int* __restrict__ csr_rc, unsigned short* __restrict__ csr_v,
    const float* __restrict__ W1, const float* __restrict__ W2,
    unsigned short* __restrict__ w1t, unsigned short* __restrict__ w2t)
{
    __shared__ float    vl[NNZ];          // 32 KB  values (f32 until writeback)
    __shared__ unsigned bmap[NN * 16];    // 32 KB  512x512 bits
    __shared__ int      cnt[NN];          // 2 KB   histogram -> cursor
    __shared__ int      sc[NN];           // 2 KB   inclusive scan (persists)
    __shared__ int      exc_rc[EXCAP];    // 4 KB
    __shared__ float    exc_v[EXCAP];     // 4 KB
    __shared__ int      wsum[8], woff[8], nexc;

    const int b   = blockIdx.x;
    const int tid = threadIdx.x;          // 0..511 == NN

    // striped weight prep: 21504 elements over 512 blocks (threads 0..41)
    {
        int pid = b + (tid << 9);
        if (pid < 7168) {
            int h = pid >> 6, k = pid & 63;
            w1t[pid] = f2bf((h < 100) ? W1[k * 100 + h] : 0.f);
        } else if (pid < 7168 + 14336) {
            int id2 = pid - 7168;
            int h = id2 >> 7, k = id2 & 127;
            w2t[id2] = f2bf((h < 100 && k < 100) ? W2[k * 100 + h] : 0.f);
        }
    }

    const int*   rb = rows + (size_t)b * NNZ;
    const int*   cb = cols + (size_t)b * NNZ;
    const float* vb = vals + (size_t)b * NNZ;
    int*         oc = csr_rc + (size_t)b * NNZ;

    // load rows ONCE into registers
    int rr[NNZ / 512];
    #pragma unroll
    for (int i = 0; i < NNZ / 512; ++i) rr[i] = rb[tid + i * 512];

    cnt[tid] = 0;
    #pragma unroll
    for (int i = 0; i < 16; ++i) bmap[tid + i * 512] = 0u;
    if (tid == 0) nexc = 0;
    __syncthreads();

    // P1: histogram (rows from regs)
    #pragma unroll
    for (int i = 0; i < NNZ / 512; ++i)
        atomicAdd(&cnt[rr[i]], 1);
    __syncthreads();

    // P2: scan via wave shuffles (2 barriers)
    const int lane = tid & 63, wid = tid >> 6;
    const int own = cnt[tid];
    int x = own;
    #pragma unroll
    for (int off = 1; off < 64; off <<= 1) {
        int y = __shfl_up(x, off);
        if (lane >= off) x += y;
    }
    if (lane == 63) wsum[wid] = x;
    __syncthreads();
    if (tid == 0) {
        int a = 0;
        #pragma unroll
        for (int w = 0; w < 8; ++w) { woff[w] = a; a += wsum[w]; }
    }
    __syncthreads();
    x += woff[wid];                        // inclusive scan over 512
    sc[tid] = x;
    row_start[b * 513 + tid + 1] = x;
    if (tid == 0) row_start[b * 513] = 0;
    cnt[tid] = x - own;                    // exclusive cursor
    __syncthreads();

    // P3: scatter + bitmap dup detection; csr_rc written straight to global
    #pragma unroll
    for (int i = 0; i < NNZ / 512; ++i) {
        int idx = tid + i * 512;
        int   r = rr[i];
        int   c = cb[idx];
        float v = vb[idx];
        unsigned bit = 1u << (c & 31);
        unsigned old = atomicOr(&bmap[(r << 4) + (c >> 5)], bit);
        int pos = atomicAdd(&cnt[r], 1);
        bool dup = (old & bit) != 0;
        int e = -1;
        if (dup) e = atomicAdd(&nexc, 1);
        if (dup && e < EXCAP) {
            oc[pos] = (r << 16) | DUMPC;   // placeholder keeps slots consistent
            vl[pos] = 0.f;
            exc_rc[e] = (r << 16) | c;
            exc_v[e]  = v;
        } else {                            // normal entry (or impossible overflow)
            oc[pos] = (r << 16) | c;
            vl[pos] = v;
        }
    }
    __syncthreads();   // fences LDS AND this block's global csr_rc writes

    // P4: parallel exception resolve (search own row segment in global csr_rc,
    //     L1-hot; f32 atomicAdd on LDS vl = multi-dup safe)
    {
        int ne = nexc < EXCAP ? nexc : EXCAP;
        for (int t = tid; t < ne; t += 512) {
            int key = exc_rc[t];
            int r   = key >> 16;
            int lo  = r ? sc[r - 1] : 0;
            int hi  = sc[r];
            for (int j = lo; j < hi; ++j) {
                if (oc[j] == key) { atomicAdd(&vl[j], exc_v[t]); break; }
            }
        }
    }
    __syncthreads();

    // P5: coalesced csr_v writeback (paired u32 stores)
    {
        unsigned* ov = (unsigned*)(csr_v + (size_t)b * NNZ);
        #pragma unroll
        for (int i = 0; i < NNZ / 1024; ++i) {
            int p = tid + i * 512;
            unsigned lo = f2bf(vl[2 * p]);
            unsigned hi = f2bf(vl[2 * p + 1]);
            ov[p] = lo | (hi << 16);
        }
    }
}

// ---------------------------------------------------------------------------
// GEMM1 (MFMA): supT(k-tiled) = bf16( emb[hyper] @ W1 )^T per batch. (r12-r14)
// ---------------------------------------------------------------------------
__global__ __launch_bounds__(256) void k_gemm1_mfma(
    const int* __restrict__ hyper, const float* __restrict__ emb,
    const unsigned short* __restrict__ w1t, unsigned short* __restrict__ supT)
{
    const int lane = threadIdx.x & 63, wave = threadIdx.x >> 6;
    const int l15 = lane & 15, g4 = lane >> 4;

    short8 bq[7][2];
    #pragma unroll
    for (int ct = 0; ct < 7; ++ct)
        #pragma unroll
        for (int kt = 0; kt < 2; ++kt)
            bq[ct][kt] = *(const short8*)(w1t + (ct * 16 + l15) * 64 + kt * 32 + g4 * 8);

    const int wsid = blockIdx.x * 4 + wave;
    #pragma unroll 2
    for (int i = 0; i < 4; ++i) {
        const int  rb   = wsid * 4 + i;
        const long base = (long)rb * 16;
        const int  rid  = hyper[base + l15];
        const float* ep = emb + (long)rid * EMB + g4 * 8;
        float4 f0 = *(const float4*)(ep);
        float4 f1 = *(const float4*)(ep + 4);
        float4 f2 = *(const float4*)(ep + 32);
        float4 f3 = *(const float4*)(ep + 36);
        short8 a0 = pack8(f0, f1);
        short8 a1 = pack8(f2, f3);

        floatx4 acc[7];
        #pragma unroll
        for (int ct = 0; ct < 7; ++ct) acc[ct] = (floatx4)0.f;
        #pragma unroll
        for (int ct = 0; ct < 7; ++ct) {
            acc[ct] = __builtin_amdgcn_mfma_f32_16x16x32_bf16(a0, bq[ct][0], acc[ct], 0, 0, 0);
            acc[ct] = __builtin_amdgcn_mfma_f32_16x16x32_bf16(a1, bq[ct][1], acc[ct], 0, 0, 0);
        }

        const int batch = rb >> 5;
        const int inrow = (rb & 31) * 16 + g4 * 4;
        #pragma unroll
        for (int ct = 0; ct < 7; ++ct) {
            int col = ct * 16 + l15;
            uint2 w;
            w.x = (unsigned)f2bf(acc[ct][0]) | ((unsigned)f2bf(acc[ct][1]) << 16);
            w.y = (unsigned)f2bf(acc[ct][2]) | ((unsigned)f2bf(acc[ct][3]) << 16);
            *(uint2*)(supT + supt_addr(batch, col, inrow)) = w;
        }
    }
}

// ---------------------------------------------------------------------------
// GEMM2 (MFMA): supT(k-tiled) = bf16( h1 @ W2 )^T, h1 bf16 [512][112]. (r12-r14)
// ---------------------------------------------------------------------------
__global__ __launch_bounds__(256) void k_gemm2_mfma(
    const unsigned short* __restrict__ h1, const unsigned short* __restrict__ w2t,
    unsigned short* __restrict__ supT)
{
    const int lane = threadIdx.x & 63, wave = threadIdx.x >> 6;
    const int l15 = lane & 15, g4 = lane >> 4;
    const int ct0 = (wave & 1) ? 4 : 0;

    short8 bq[4][4];
    #pragma unroll
    for (int ctl = 0; ctl < 4; ++ctl) {
        int ct = ct0 + ctl;
        if (ct < 7)
            #pragma unroll
            for (int kt = 0; kt < 4; ++kt)
                bq[ctl][kt] = *(const short8*)(w2t + (ct * 16 + l15) * 128 + kt * 32 + g4 * 8);
    }

    const int wp = blockIdx.x * 2 + (wave >> 1);
    #pragma unroll 2
    for (int i = 0; i < 8; ++i) {
        const int  rb   = wp * 8 + i;
        const long base = (long)rb * 16;
        const unsigned short* rp = h1 + (size_t)(base + l15) * 112;

        short8 a[4];
        #pragma unroll
        for (int kt = 0; kt < 4; ++kt) {
            int k0 = kt * 32 + g4 * 8;
            short8 av = (short8)(short)0;
            if (k0 < 112) av = *(const short8*)(rp + k0);
            a[kt] = av;
        }

        floatx4 acc[4];
        #pragma unroll
        for (int ctl = 0; ctl < 4; ++ctl) acc[ctl] = (floatx4)0.f;
        #pragma unroll
        for (int ctl = 0; ctl < 4; ++ctl) {
            if (ct0 + ctl < 7) {
                #pragma unroll
                for (int kt = 0; kt < 4; ++kt)
                    acc[ctl] = __builtin_amdgcn_mfma_f32_16x16x32_bf16(a[kt], bq[ctl][kt], acc[ctl], 0, 0, 0);
            }
        }

        const int batch = rb >> 5;
        const int inrow = (rb & 31) * 16 + g4 * 4;
        #pragma unroll
        for (int ctl = 0; ctl < 4; ++ctl) {
            if (ct0 + ctl < 7) {
                int col = (ct0 + ctl) * 16 + l15;
                uint2 w;
                w.x = (unsigned)f2bf(acc[ctl][0]) | ((unsigned)f2bf(acc[ctl][1]) << 16);
                w.y = (unsigned)f2bf(acc[ctl][2]) | ((unsigned)f2bf(acc[ctl][3]) << 16);
                *(uint2*)(supT + supt_addr(batch, col, inrow)) = w;
            }
        }
    }
}

// ---------------------------------------------------------------------------
// SpMM + bias via dense-A MFMA, K-SPLIT 8-wave version (verified r13/r14,
// unchanged).
// ---------------------------------------------------------------------------
template<bool FINAL>
__global__ __launch_bounds__(512) void k_spmm_mfma(
    const int* __restrict__ row_st, const int* __restrict__ rc,
    const unsigned short* __restrict__ vv, const unsigned short* __restrict__ supT,
    const float* __restrict__ bias, unsigned short* __restrict__ h1,
    float* __restrict__ out)
{
    __shared__ unsigned short Ad[64 * 512 + 64];  // 65,664 B -> 2 blocks/CU

    const int tid    = threadIdx.x;
    // XCD-locality swizzle (8 XCDs, round-robin blockIdx%8 -> XCD)
    const int xcd    = blockIdx.x & 7;
    const int local  = blockIdx.x >> 3;          // 0..511
    const int batch  = xcd * 64 + (local >> 3);
    const int stripe = local & 7;
    const int r0     = stripe * 64;

    // P0: issue CSR loads EARLY (use-late after the zero phase)
    const int s0 = row_st[batch * 513 + r0];
    const int e0 = row_st[batch * 513 + r0 + 64];
    const int*            rcb = rc + (size_t)batch * NNZ;
    const unsigned short* vvb = vv + (size_t)batch * NNZ;
    int            pc[3];
    unsigned short pv[3];
    #pragma unroll
    for (int i = 0; i < 3; ++i) {
        int idx = s0 + tid + i * 512;
        bool ok = idx < e0;
        pc[i] = ok ? rcb[idx] : 0;
        pv[i] = ok ? vvb[idx] : 0;
    }

    // P1: zero A_d (4104 uint4)
    {
        uint4* z = (uint4*)Ad;
        #pragma unroll
        for (int i = 0; i < 9; ++i) {
            int idx = tid + i * 512;
            if (idx < 4104) z[idx] = make_uint4(0u, 0u, 0u, 0u);
        }
    }
    __syncthreads();

    // P2: scatter from regs; lane-linear sub-tile addressing.
    #pragma unroll
    for (int i = 0; i < 3; ++i) {
        int idx = s0 + tid + i * 512;
        if (idx < e0) {
            int r = ((pc[i] >> 16) & 0xffff) - r0;
            int c = pc[i] & 0xffff;
            int a = (c < 512)
                ? ((r >> 4) * 8192 + (c >> 5) * 512 + ((c >> 3) & 3) * 128 + (r & 15) * 8 + (c & 7))
                : (64 * 512 + (tid & 63));
            Ad[a] = pv[i];
        }
    }
    // overflow fallback (cnt > 1536: statistically never, correctness only)
    for (int idx = s0 + 1536 + tid; idx < e0; idx += 512) {
        int p = rcb[idx];
        int r = ((p >> 16) & 0xffff) - r0;
        int c = p & 0xffff;
        int a = (c < 512)
            ? ((r >> 4) * 8192 + (c >> 5) * 512 + ((c >> 3) & 3) * 128 + (r & 15) * 8 + (c & 7))
            : (64 * 512 + (tid & 63));
        Ad[a] = vvb[idx];
    }
    __syncthreads();

    // P3: MFMA — wave (kh, ng): kt in [kh*8, kh*8+8), n-tiles {2ng, 2ng+1}
    const int lane = tid & 63, wave = tid >> 6;
    const int l15 = lane & 15, g4 = lane >> 4;
    const int ng  = wave & 3, kh = wave >> 2;
    const int nt0 = ng * 2;
    const bool two = (nt0 + 1) < 7;              // ng=3 owns only n-tile 6
    const int ktb = kh * 8;

    const unsigned short* b0p = supT + (size_t)batch * 57344 + (size_t)ktb * 3584
                               + (nt0 * 16 + l15) * 32 + g4 * 8;
    const unsigned short* b1p = b0p + 512;       // next n-tile
    const unsigned short* ap  = Ad + (size_t)ktb * 512 + lane * 8;  // lane-linear

    floatx4 acc[2][4];
    #pragma unroll
    for (int n = 0; n < 2; ++n)
        #pragma unroll
        for (int m = 0; m < 4; ++m) acc[n][m] = (floatx4)0.f;

    #pragma unroll 4
    for (int kt = 0; kt < 8; ++kt) {
        short8 b0 = *(const short8*)(b0p + (size_t)kt * 3584);
        short8 b1 = (short8)(short)0;
        if (two) b1 = *(const short8*)(b1p + (size_t)kt * 3584);
        #pragma unroll
        for (int m = 0; m < 4; ++m) {
            short8 a = *(const short8*)(ap + m * 8192 + kt * 512);
            acc[0][m] = __builtin_amdgcn_mfma_f32_16x16x32_bf16(a, b0, acc[0][m], 0, 0, 0);
            if (two)
                acc[1][m] = __builtin_amdgcn_mfma_f32_16x16x32_bf16(a, b1, acc[1][m], 0, 0, 0);
        }
    }
    __syncthreads();                             // all MFMAs done; A_d dead

    // P4: k-half reduction through LDS. redu[slot:4][i:32][lane:64] f32 (32KB)
    float* redu = (float*)Ad;
    if (kh == 1) {
        #pragma unroll
        for (int nn = 0; nn < 2; ++nn)
            #pragma unroll
            for (int m = 0; m < 4; ++m)
                #pragma unroll
                for (int q = 0; q < 4; ++q)
                    redu[ng * 2048 + ((nn * 4 + m) * 4 + q) * 64 + lane] = acc[nn][m][q];
    }
    __syncthreads();

    // P5: waves kh=0 add partner partials and stage C (+bias) at byte 32768
    if (kh == 0) {
        #pragma unroll
        for (int nn = 0; nn < 2; ++nn)
            #pragma unroll
            for (int m = 0; m < 4; ++m)
                #pragma unroll
                for (int q = 0; q < 4; ++q)
                    acc[nn][m][q] += redu[ng * 2048 + ((nn * 4 + m) * 4 + q) * 64 + lane];

        if (FINAL) {
            float* st = (float*)((char*)Ad + 32768);           // [64][112] f32
            #pragma unroll
            for (int nn = 0; nn < 2; ++nn) {
                int nt = nt0 + nn;
                if (nt >= 7) break;
                int col = nt * 16 + l15;
                float bi = (col < HID) ? bias[col] : 0.f;
                #pragma unroll
                for (int m = 0; m < 4; ++m) {
                    int row = m * 16 + g4 * 4;
                    #pragma unroll
                    for (int q = 0; q < 4; ++q)
                        st[(row + q) * 112 + col] = acc[nn][m][q] + bi;
                }
            }
        } else {
            unsigned short* st = (unsigned short*)((char*)Ad + 32768);  // [64][112] bf16
            #pragma unroll
            for (int nn = 0; nn < 2; ++nn) {
                int nt = nt0 + nn;
                if (nt >= 7) break;
                int col = nt * 16 + l15;
                float bi = (col < HID) ? bias[col] : 0.f;      // pad cols: acc==0 -> 0
                #pragma unroll
                for (int m = 0; m < 4; ++m) {
                    int row = m * 16 + g4 * 4;
                    #pragma unroll
                    for (int q = 0; q < 4; ++q)
                        st[(row + q) * 112 + col] = f2bf(acc[nn][m][q] + bi);
                }
            }
        }
    }
    __syncthreads();

    // P6: coalesced copy-out, all 512 threads
    if (FINAL) {
        const float* st = (const float*)((char*)Ad + 32768);
        #pragma unroll
        for (int i = 0; i < 4; ++i) {
            int flat = tid + i * 512;
            if (flat < 1600) {                   // 64 rows x 25 float4
                int row = flat / 25, wi = flat - row * 25;
                float4 v = *(const float4*)(st + row * 112 + wi * 4);
                *(float4*)(out + ((size_t)batch * NN + r0 + row) * HID + wi * 4) = v;
            }
        }
    } else {
        const unsigned short* st = (const unsigned short*)((char*)Ad + 32768);
        #pragma unroll
        for (int i = 0; i < 2; ++i) {
            int flat = tid + i * 512;
            if (flat < 896) {                    // 64 rows x 14 uint4
                int row = flat / 14, wi = flat - row * 14;
                uint4 v = *(const uint4*)(st + row * 112 + wi * 8);
                *(uint4*)(h1 + ((size_t)batch * NN + r0 + row) * 112 + wi * 8) = v;
            }
        }
    }
}

// ---------------------------------------------------------------------------
extern "C" void kernel_launch(void* const* d_in, const int* in_sizes, int n_in,
                              void* d_out, int out_size, void* d_ws, size_t ws_size,
                              hipStream_t stream)
{
    const int*   hyper = (const int*)  d_in[0];
    const int*   arows = (const int*)  d_in[1];
    const int*   acols = (const int*)  d_in[2];
    const float* avals = (const float*)d_in[3];
    const float* emb   = (const float*)d_in[4];
    const float* W1    = (const float*)d_in[5];
    const float* b1    = (const float*)d_in[6];
    const float* W2    = (const float*)d_in[7];
    const float* b2    = (const float*)d_in[8];

    float*          out = (float*)d_out;
    unsigned short* h1  = (unsigned short*)d_out;   // bf16 [B][512][112] view
    char*           ws  = (char*)d_ws;

    int*            csr_rc = (int*)           (ws + OFF_CSR_RC);
    unsigned short* csr_v  = (unsigned short*)(ws + OFF_CSR_V);
    int*            row_st = (int*)           (ws + OFF_ROWST);
    unsigned short* supT   = (unsigned short*)(ws + OFF_SUPT);
    unsigned short* w1t    = (unsigned short*)(ws + OFF_W1T);
    unsigned short* w2t    = (unsigned short*)(ws + OFF_W2T);

    // CSR build v3 (single round, 2 blocks/CU) + striped weight prep
    k_csr_build<<<BB, 512, 0, stream>>>(arows, acols, avals, row_st,
                                        csr_rc, csr_v, W1, W2, w1t, w2t);

    // 1) supT(k-tiled) = bf16(emb[hyper] @ W1)^T (per batch)
    k_gemm1_mfma<<<1024, 256, 0, stream>>>(hyper, emb, w1t, supT);
    // 2) h1 = bf16(A @ sup1 + b1) -> d_out (bf16 [512][112])
    k_spmm_mfma<false><<<BB * 8, 512, 0, stream>>>(row_st, csr_rc, csr_v, supT, b1, h1, out);
    // 3) supT(k-tiled) = bf16(h1 @ W2)^T (per batch)
    k_gemm2_mfma<<<1024, 256, 0, stream>>>(h1, w2t, supT);
    // 4) out = A @ sup2 + b2 -> d_out (fp32)
    k_spmm_mfma<true><<<BB * 8, 512, 0, stream>>>(row_st, csr_rc, csr_v, supT, b2, h1, out);
}

// Round 16
// 205.981 us; speedup vs baseline: 1.8134x; 1.0050x over previous
//
#include <hip/hip_runtime.h>

// Problem constants (match reference setup_inputs)
#define BB   512
#define NN   512
#define NNZ  8192
#define EMB  64
#define HID  100
#define DUMPC 512            // dump "column" for dup placeholders -> LDS tail in spmm
#define EXCAP 1024           // exception-list capacity (mean ~128, 80-sigma margin)

// ---------------------------------------------------------------------------
// ws layout (bytes):
//   [0)          csr_rc  int  [B*NNZ]  (row<<16|col)   16,777,216
//   [16777216)   csr_v   bf16 [B*NNZ]                   8,388,608
//   [25165824)   row_st  int  [B*513]                   1,050,624
//   [26216448)   supT    bf16 [B][16kt][112col][32k]   58,720,256   (k-tiled)
//   [84936704)   w1t     bf16 [112][64]                    14,336
//   [84951040)   w2t     bf16 [112][128]                   28,672
// h1 (bf16 [B][512][112]) lives in d_out; overwritten by final fp32 output.
// ---------------------------------------------------------------------------
#define OFF_CSR_RC  0
#define OFF_CSR_V   16777216
#define OFF_ROWST   25165824
#define OFF_SUPT    26216448
#define OFF_W1T     84936704
#define OFF_W2T     84951040

typedef __attribute__((ext_vector_type(8))) short short8;
typedef __attribute__((ext_vector_type(4))) float floatx4;

__device__ __forceinline__ unsigned short f2bf(float f) {
    unsigned u = __float_as_uint(f);
    unsigned r = (u + 0x7fffu + ((u >> 16) & 1u)) >> 16;
    return (unsigned short)r;
}

__device__ __forceinline__ short8 pack8(float4 a, float4 b) {
    short8 s;
    s[0] = (short)f2bf(a.x); s[1] = (short)f2bf(a.y);
    s[2] = (short)f2bf(a.z); s[3] = (short)f2bf(a.w);
    s[4] = (short)f2bf(b.x); s[5] = (short)f2bf(b.y);
    s[6] = (short)f2bf(b.z); s[7] = (short)f2bf(b.w);
    return s;
}

// supT k-tiled addressing: elem(b, col, k) = b*57344 + (k>>5)*3584 + col*32 + (k&31)
__device__ __forceinline__ size_t supt_addr(int batch, int col, int k) {
    return (size_t)batch * 57344 + (size_t)(k >> 5) * 3584 + (size_t)col * 32 + (k & 31);
}

// ---------------------------------------------------------------------------
// CSR build v3 (verified r15): one co-resident round, bitmap dup-merge,
// direct-global csr_rc, rows in regs, striped weight prep.
// ---------------------------------------------------------------------------
__global__ __launch_bounds__(512) void k_csr_build(
    const int* __restrict__ rows, const int* __restrict__ cols,
    const float* __restrict__ vals, int* __restrict__ row_start,
    int* __restrict__ csr_rc, unsigned short* __restrict__ csr_v,
    const float* __restrict__ W1, const float* __restrict__ W2,
    unsigned short* __restrict__ w1t, unsigned short* __restrict__ w2t)
{
    __shared__ float    vl[NNZ];          // 32 KB  values (f32 until writeback)
    __shared__ unsigned bmap[NN * 16];    // 32 KB  512x512 bits
    __shared__ int      cnt[NN];          // 2 KB   histogram -> cursor
    __shared__ int      sc[NN];           // 2 KB   inclusive scan (persists)
    __shared__ int      exc_rc[EXCAP];    // 4 KB
    __shared__ float    exc_v[EXCAP];     // 4 KB
    __shared__ int      wsum[8], woff[8], nexc;

    const int b   = blockIdx.x;
    const int tid = threadIdx.x;          // 0..511 == NN

    // striped weight prep: 21504 elements over 512 blocks (threads 0..41)
    {
        int pid = b + (tid << 9);
        if (pid < 7168) {
            int h = pid >> 6, k = pid & 63;
            w1t[pid] = f2bf((h < 100) ? W1[k * 100 + h] : 0.f);
        } else if (pid < 7168 + 14336) {
            int id2 = pid - 7168;
            int h = id2 >> 7, k = id2 & 127;
            w2t[id2] = f2bf((h < 100 && k < 100) ? W2[k * 100 + h] : 0.f);
        }
    }

    const int*   rb = rows + (size_t)b * NNZ;
    const int*   cb = cols + (size_t)b * NNZ;
    const float* vb = vals + (size_t)b * NNZ;
    int*         oc = csr_rc + (size_t)b * NNZ;

    // load rows ONCE into registers
    int rr[NNZ / 512];
    #pragma unroll
    for (int i = 0; i < NNZ / 512; ++i) rr[i] = rb[tid + i * 512];

    cnt[tid] = 0;
    #pragma unroll
    for (int i = 0; i < 16; ++i) bmap[tid + i * 512] = 0u;
    if (tid == 0) nexc = 0;
    __syncthreads();

    // P1: histogram (rows from regs)
    #pragma unroll
    for (int i = 0; i < NNZ / 512; ++i)
        atomicAdd(&cnt[rr[i]], 1);
    __syncthreads();

    // P2: scan via wave shuffles (2 barriers)
    const int lane = tid & 63, wid = tid >> 6;
    const int own = cnt[tid];
    int x = own;
    #pragma unroll
    for (int off = 1; off < 64; off <<= 1) {
        int y = __shfl_up(x, off);
        if (lane >= off) x += y;
    }
    if (lane == 63) wsum[wid] = x;
    __syncthreads();
    if (tid == 0) {
        int a = 0;
        #pragma unroll
        for (int w = 0; w < 8; ++w) { woff[w] = a; a += wsum[w]; }
    }
    __syncthreads();
    x += woff[wid];                        // inclusive scan over 512
    sc[tid] = x;
    row_start[b * 513 + tid + 1] = x;
    if (tid == 0) row_start[b * 513] = 0;
    cnt[tid] = x - own;                    // exclusive cursor
    __syncthreads();

    // P3: scatter + bitmap dup detection; csr_rc written straight to global
    #pragma unroll
    for (int i = 0; i < NNZ / 512; ++i) {
        int idx = tid + i * 512;
        int   r = rr[i];
        int   c = cb[idx];
        float v = vb[idx];
        unsigned bit = 1u << (c & 31);
        unsigned old = atomicOr(&bmap[(r << 4) + (c >> 5)], bit);
        int pos = atomicAdd(&cnt[r], 1);
        bool dup = (old & bit) != 0;
        int e = -1;
        if (dup) e = atomicAdd(&nexc, 1);
        if (dup && e < EXCAP) {
            oc[pos] = (r << 16) | DUMPC;   // placeholder keeps slots consistent
            vl[pos] = 0.f;
            exc_rc[e] = (r << 16) | c;
            exc_v[e]  = v;
        } else {
            oc[pos] = (r << 16) | c;
            vl[pos] = v;
        }
    }
    __syncthreads();   // fences LDS AND this block's global csr_rc writes

    // P4: parallel exception resolve
    {
        int ne = nexc < EXCAP ? nexc : EXCAP;
        for (int t = tid; t < ne; t += 512) {
            int key = exc_rc[t];
            int r   = key >> 16;
            int lo  = r ? sc[r - 1] : 0;
            int hi  = sc[r];
            for (int j = lo; j < hi; ++j) {
                if (oc[j] == key) { atomicAdd(&vl[j], exc_v[t]); break; }
            }
        }
    }
    __syncthreads();

    // P5: coalesced csr_v writeback (paired u32 stores)
    {
        unsigned* ov = (unsigned*)(csr_v + (size_t)b * NNZ);
        #pragma unroll
        for (int i = 0; i < NNZ / 1024; ++i) {
            int p = tid + i * 512;
            unsigned lo = f2bf(vl[2 * p]);
            unsigned hi = f2bf(vl[2 * p + 1]);
            ov[p] = lo | (hi << 16);
        }
    }
}

// ---------------------------------------------------------------------------
// GEMM1 (MFMA): supT(k-tiled) = bf16( emb[hyper] @ W1 )^T per batch. (r12-r15)
// ---------------------------------------------------------------------------
__global__ __launch_bounds__(256) void k_gemm1_mfma(
    const int* __restrict__ hyper, const float* __restrict__ emb,
    const unsigned short* __restrict__ w1t, unsigned short* __restrict__ supT)
{
    const int lane = threadIdx.x & 63, wave = threadIdx.x >> 6;
    const int l15 = lane & 15, g4 = lane >> 4;

    short8 bq[7][2];
    #pragma unroll
    for (int ct = 0; ct < 7; ++ct)
        #pragma unroll
        for (int kt = 0; kt < 2; ++kt)
            bq[ct][kt] = *(const short8*)(w1t + (ct * 16 + l15) * 64 + kt * 32 + g4 * 8);

    const int wsid = blockIdx.x * 4 + wave;
    #pragma unroll 2
    for (int i = 0; i < 4; ++i) {
        const int  rb   = wsid * 4 + i;
        const long base = (long)rb * 16;
        const int  rid  = hyper[base + l15];
        const float* ep = emb + (long)rid * EMB + g4 * 8;
        float4 f0 = *(const float4*)(ep);
        float4 f1 = *(const float4*)(ep + 4);
        float4 f2 = *(const float4*)(ep + 32);
        float4 f3 = *(const float4*)(ep + 36);
        short8 a0 = pack8(f0, f1);
        short8 a1 = pack8(f2, f3);

        floatx4 acc[7];
        #pragma unroll
        for (int ct = 0; ct < 7; ++ct) acc[ct] = (floatx4)0.f;
        #pragma unroll
        for (int ct = 0; ct < 7; ++ct) {
            acc[ct] = __builtin_amdgcn_mfma_f32_16x16x32_bf16(a0, bq[ct][0], acc[ct], 0, 0, 0);
            acc[ct] = __builtin_amdgcn_mfma_f32_16x16x32_bf16(a1, bq[ct][1], acc[ct], 0, 0, 0);
        }

        const int batch = rb >> 5;
        const int inrow = (rb & 31) * 16 + g4 * 4;
        #pragma unroll
        for (int ct = 0; ct < 7; ++ct) {
            int col = ct * 16 + l15;
            uint2 w;
            w.x = (unsigned)f2bf(acc[ct][0]) | ((unsigned)f2bf(acc[ct][1]) << 16);
            w.y = (unsigned)f2bf(acc[ct][2]) | ((unsigned)f2bf(acc[ct][3]) << 16);
            *(uint2*)(supT + supt_addr(batch, col, inrow)) = w;
        }
    }
}

// ---------------------------------------------------------------------------
// GEMM2 (MFMA): supT(k-tiled) = bf16( h1 @ W2 )^T, h1 bf16 [512][112]. (r12-r15)
// ---------------------------------------------------------------------------
__global__ __launch_bounds__(256) void k_gemm2_mfma(
    const unsigned short* __restrict__ h1, const unsigned short* __restrict__ w2t,
    unsigned short* __restrict__ supT)
{
    const int lane = threadIdx.x & 63, wave = threadIdx.x >> 6;
    const int l15 = lane & 15, g4 = lane >> 4;
    const int ct0 = (wave & 1) ? 4 : 0;

    short8 bq[4][4];
    #pragma unroll
    for (int ctl = 0; ctl < 4; ++ctl) {
        int ct = ct0 + ctl;
        if (ct < 7)
            #pragma unroll
            for (int kt = 0; kt < 4; ++kt)
                bq[ctl][kt] = *(const short8*)(w2t + (ct * 16 + l15) * 128 + kt * 32 + g4 * 8);
    }

    const int wp = blockIdx.x * 2 + (wave >> 1);
    #pragma unroll 2
    for (int i = 0; i < 8; ++i) {
        const int  rb   = wp * 8 + i;
        const long base = (long)rb * 16;
        const unsigned short* rp = h1 + (size_t)(base + l15) * 112;

        short8 a[4];
        #pragma unroll
        for (int kt = 0; kt < 4; ++kt) {
            int k0 = kt * 32 + g4 * 8;
            short8 av = (short8)(short)0;
            if (k0 < 112) av = *(const short8*)(rp + k0);
            a[kt] = av;
        }

        floatx4 acc[4];
        #pragma unroll
        for (int ctl = 0; ctl < 4; ++ctl) acc[ctl] = (floatx4)0.f;
        #pragma unroll
        for (int ctl = 0; ctl < 4; ++ctl) {
            if (ct0 + ctl < 7) {
                #pragma unroll
                for (int kt = 0; kt < 4; ++kt)
                    acc[ctl] = __builtin_amdgcn_mfma_f32_16x16x32_bf16(a[kt], bq[ctl][kt], acc[ctl], 0, 0, 0);
            }
        }

        const int batch = rb >> 5;
        const int inrow = (rb & 31) * 16 + g4 * 4;
        #pragma unroll
        for (int ctl = 0; ctl < 4; ++ctl) {
            if (ct0 + ctl < 7) {
                int col = (ct0 + ctl) * 16 + l15;
                uint2 w;
                w.x = (unsigned)f2bf(acc[ctl][0]) | ((unsigned)f2bf(acc[ctl][1]) << 16);
                w.y = (unsigned)f2bf(acc[ctl][2]) | ((unsigned)f2bf(acc[ctl][3]) << 16);
                *(uint2*)(supT + supt_addr(batch, col, inrow)) = w;
            }
        }
    }
}

// ---------------------------------------------------------------------------
// SpMM + bias via dense-A MFMA, K-SPLIT 8-wave (r13-r15) + B-FRAG PRELOAD:
// all 16 B fragments (64 VGPRs) are loaded in P0, before the zero/scatter
// phases — their L2 latency hides under P1/P2 + 2 barriers (same T14 move
// that already covers the CSR entries). P3 is then pure ds_read+MFMA.
// __launch_bounds__(512, 4) pins VGPR <= 128 so 2 blocks/CU (16 waves) is
// preserved — mandatory (>128 VGPR would mean 1 block/CU = the r7 failure).
// ---------------------------------------------------------------------------
template<bool FINAL>
__global__ __launch_bounds__(512, 4) void k_spmm_mfma(
    const int* __restrict__ row_st, const int* __restrict__ rc,
    const unsigned short* __restrict__ vv, const unsigned short* __restrict__ supT,
    const float* __restrict__ bias, unsigned short* __restrict__ h1,
    float* __restrict__ out)
{
    __shared__ unsigned short Ad[64 * 512 + 64];  // 65,664 B -> 2 blocks/CU

    const int tid    = threadIdx.x;
    // XCD-locality swizzle (8 XCDs, round-robin blockIdx%8 -> XCD)
    const int xcd    = blockIdx.x & 7;
    const int local  = blockIdx.x >> 3;          // 0..511
    const int batch  = xcd * 64 + (local >> 3);
    const int stripe = local & 7;
    const int r0     = stripe * 64;

    const int lane = tid & 63, wave = tid >> 6;
    const int l15 = lane & 15, g4 = lane >> 4;
    const int ng  = wave & 3, kh = wave >> 2;
    const int nt0 = ng * 2;
    const bool two = (nt0 + 1) < 7;              // ng=3 owns only n-tile 6
    const int ktb = kh * 8;

    // P0a: issue CSR loads EARLY
    const int s0 = row_st[batch * 513 + r0];
    const int e0 = row_st[batch * 513 + r0 + 64];
    const int*            rcb = rc + (size_t)batch * NNZ;
    const unsigned short* vvb = vv + (size_t)batch * NNZ;
    int            pc[3];
    unsigned short pv[3];
    #pragma unroll
    for (int i = 0; i < 3; ++i) {
        int idx = s0 + tid + i * 512;
        bool ok = idx < e0;
        pc[i] = ok ? rcb[idx] : 0;
        pv[i] = ok ? vvb[idx] : 0;
    }

    // P0b: issue ALL B-fragment loads EARLY (L2 latency hides under P1/P2)
    const unsigned short* b0p = supT + (size_t)batch * 57344 + (size_t)ktb * 3584
                               + (nt0 * 16 + l15) * 32 + g4 * 8;
    const unsigned short* b1p = b0p + 512;       // next n-tile
    short8 bfr[16];
    #pragma unroll
    for (int kt = 0; kt < 8; ++kt) {
        bfr[2 * kt] = *(const short8*)(b0p + (size_t)kt * 3584);
        if (two) bfr[2 * kt + 1] = *(const short8*)(b1p + (size_t)kt * 3584);
        else     bfr[2 * kt + 1] = (short8)(short)0;
    }

    // P1: zero A_d (4104 uint4)
    {
        uint4* z = (uint4*)Ad;
        #pragma unroll
        for (int i = 0; i < 9; ++i) {
            int idx = tid + i * 512;
            if (idx < 4104) z[idx] = make_uint4(0u, 0u, 0u, 0u);
        }
    }
    __syncthreads();

    // P2: scatter from regs; lane-linear sub-tile addressing.
    #pragma unroll
    for (int i = 0; i < 3; ++i) {
        int idx = s0 + tid + i * 512;
        if (idx < e0) {
            int r = ((pc[i] >> 16) & 0xffff) - r0;
            int c = pc[i] & 0xffff;
            int a = (c < 512)
                ? ((r >> 4) * 8192 + (c >> 5) * 512 + ((c >> 3) & 3) * 128 + (r & 15) * 8 + (c & 7))
                : (64 * 512 + (tid & 63));
            Ad[a] = pv[i];
        }
    }
    // overflow fallback (cnt > 1536: statistically never, correctness only)
    for (int idx = s0 + 1536 + tid; idx < e0; idx += 512) {
        int p = rcb[idx];
        int r = ((p >> 16) & 0xffff) - r0;
        int c = p & 0xffff;
        int a = (c < 512)
            ? ((r >> 4) * 8192 + (c >> 5) * 512 + ((c >> 3) & 3) * 128 + (r & 15) * 8 + (c & 7))
            : (64 * 512 + (tid & 63));
        Ad[a] = vvb[idx];
    }
    __syncthreads();

    // P3: pure LDS-read + MFMA (B already in registers)
    const unsigned short* ap = Ad + (size_t)ktb * 512 + lane * 8;  // lane-linear

    floatx4 acc[2][4];
    #pragma unroll
    for (int n = 0; n < 2; ++n)
        #pragma unroll
        for (int m = 0; m < 4; ++m) acc[n][m] = (floatx4)0.f;

    #pragma unroll
    for (int kt = 0; kt < 8; ++kt) {
        #pragma unroll
        for (int m = 0; m < 4; ++m) {
            short8 a = *(const short8*)(ap + m * 8192 + kt * 512);
            acc[0][m] = __builtin_amdgcn_mfma_f32_16x16x32_bf16(a, bfr[2 * kt], acc[0][m], 0, 0, 0);
            if (two)
                acc[1][m] = __builtin_amdgcn_mfma_f32_16x16x32_bf16(a, bfr[2 * kt + 1], acc[1][m], 0, 0, 0);
        }
    }
    __syncthreads();                             // all MFMAs done; A_d dead

    // P4: k-half reduction through LDS. redu[slot:4][i:32][lane:64] f32 (32KB)
    float* redu = (float*)Ad;
    if (kh == 1) {
        #pragma unroll
        for (int nn = 0; nn < 2; ++nn)
            #pragma unroll
            for (int m = 0; m < 4; ++m)
                #pragma unroll
                for (int q = 0; q < 4; ++q)
                    redu[ng * 2048 + ((nn * 4 + m) * 4 + q) * 64 + lane] = acc[nn][m][q];
    }
    __syncthreads();

    // P5: waves kh=0 add partner partials and stage C (+bias) at byte 32768
    if (kh == 0) {
        #pragma unroll
        for (int nn = 0; nn < 2; ++nn)
            #pragma unroll
            for (int m = 0; m < 4; ++m)
                #pragma unroll
                for (int q = 0; q < 4; ++q)
                    acc[nn][m][q] += redu[ng * 2048 + ((nn * 4 + m) * 4 + q) * 64 + lane];

        if (FINAL) {
            float* st = (float*)((char*)Ad + 32768);           // [64][112] f32
            #pragma unroll
            for (int nn = 0; nn < 2; ++nn) {
                int nt = nt0 + nn;
                if (nt >= 7) break;
                int col = nt * 16 + l15;
                float bi = (col < HID) ? bias[col] : 0.f;
                #pragma unroll
                for (int m = 0; m < 4; ++m) {
                    int row = m * 16 + g4 * 4;
                    #pragma unroll
                    for (int q = 0; q < 4; ++q)
                        st[(row + q) * 112 + col] = acc[nn][m][q] + bi;
                }
            }
        } else {
            unsigned short* st = (unsigned short*)((char*)Ad + 32768);  // [64][112] bf16
            #pragma unroll
            for (int nn = 0; nn < 2; ++nn) {
                int nt = nt0 + nn;
                if (nt >= 7) break;
                int col = nt * 16 + l15;
                float bi = (col < HID) ? bias[col] : 0.f;      // pad cols: acc==0 -> 0
                #pragma unroll
                for (int m = 0; m < 4; ++m) {
                    int row = m * 16 + g4 * 4;
                    #pragma unroll
                    for (int q = 0; q < 4; ++q)
                        st[(row + q) * 112 + col] = f2bf(acc[nn][m][q] + bi);
                }
            }
        }
    }
    __syncthreads();

    // P6: coalesced copy-out, all 512 threads
    if (FINAL) {
        const float* st = (const float*)((char*)Ad + 32768);
        #pragma unroll
        for (int i = 0; i < 4; ++i) {
            int flat = tid + i * 512;
            if (flat < 1600) {                   // 64 rows x 25 float4
                int row = flat / 25, wi = flat - row * 25;
                float4 v = *(const float4*)(st + row * 112 + wi * 4);
                *(float4*)(out + ((size_t)batch * NN + r0 + row) * HID + wi * 4) = v;
            }
        }
    } else {
        const unsigned short* st = (const unsigned short*)((char*)Ad + 32768);
        #pragma unroll
        for (int i = 0; i < 2; ++i) {
            int flat = tid + i * 512;
            if (flat < 896) {                    // 64 rows x 14 uint4
                int row = flat / 14, wi = flat - row * 14;
                uint4 v = *(const uint4*)(st + row * 112 + wi * 8);
                *(uint4*)(h1 + ((size_t)batch * NN + r0 + row) * 112 + wi * 8) = v;
            }
        }
    }
}

// ---------------------------------------------------------------------------
extern "C" void kernel_launch(void* const* d_in, const int* in_sizes, int n_in,
                              void* d_out, int out_size, void* d_ws, size_t ws_size,
                              hipStream_t stream)
{
    const int*   hyper = (const int*)  d_in[0];
    const int*   arows = (const int*)  d_in[1];
    const int*   acols = (const int*)  d_in[2];
    const float* avals = (const float*)d_in[3];
    const float* emb   = (const float*)d_in[4];
    const float* W1    = (const float*)d_in[5];
    const float* b1    = (const float*)d_in[6];
    const float* W2    = (const float*)d_in[7];
    const float* b2    = (const float*)d_in[8];

    float*          out = (float*)d_out;
    unsigned short* h1  = (unsigned short*)d_out;   // bf16 [B][512][112] view
    char*           ws  = (char*)d_ws;

    int*            csr_rc = (int*)           (ws + OFF_CSR_RC);
    unsigned short* csr_v  = (unsigned short*)(ws + OFF_CSR_V);
    int*            row_st = (int*)           (ws + OFF_ROWST);
    unsigned short* supT   = (unsigned short*)(ws + OFF_SUPT);
    unsigned short* w1t    = (unsigned short*)(ws + OFF_W1T);
    unsigned short* w2t    = (unsigned short*)(ws + OFF_W2T);

    // CSR build v3 (single round, 2 blocks/CU) + striped weight prep
    k_csr_build<<<BB, 512, 0, stream>>>(arows, acols, avals, row_st,
                                        csr_rc, csr_v, W1, W2, w1t, w2t);

    // 1) supT(k-tiled) = bf16(emb[hyper] @ W1)^T (per batch)
    k_gemm1_mfma<<<1024, 256, 0, stream>>>(hyper, emb, w1t, supT);
    // 2) h1 = bf16(A @ sup1 + b1) -> d_out (bf16 [512][112])
    k_spmm_mfma<false><<<BB * 8, 512, 0, stream>>>(row_st, csr_rc, csr_v, supT, b1, h1, out);
    // 3) supT(k-tiled) = bf16(h1 @ W2)^T (per batch)
    k_gemm2_mfma<<<1024, 256, 0, stream>>>(h1, w2t, supT);
    // 4) out = A @ sup2 + b2 -> d_out (fp32)
    k_spmm_mfma<true><<<BB * 8, 512, 0, stream>>>(row_st, csr_rc, csr_v, supT, b2, h1, out);
}